// Round 2
// baseline (474.708 us; speedup 1.0000x reference)
//
#include <hip/hip_runtime.h>

typedef unsigned short u16;
typedef __attribute__((ext_vector_type(8))) short short8;
typedef __attribute__((ext_vector_type(4))) float f32x4;

__device__ __forceinline__ u16 f2bf(float f) {
  union { float f; unsigned u; } a; a.f = f;
  unsigned u = a.u;
  u += 0x7fffu + ((u >> 16) & 1u);
  return (u16)(u >> 16);
}

// ---------------- transpose + convert: dst[c][r] = (bf16)src[r][c] ----------------
template<bool SRC_F32>
__global__ __launch_bounds__(256)
void transpose_cvt_kernel(const void* src_, u16* dst, int R, int C,
                          long sbatch, long dbatch) {
  const int bz = blockIdx.z;
  const float* sf = (const float*)src_ + (long)bz * sbatch;
  const u16*   sh = (const u16*)src_ + (long)bz * sbatch;
  dst += (long)bz * dbatch;
  __shared__ u16 tile[32][33];
  const int c0 = blockIdx.x * 32, r0 = blockIdx.y * 32;
  const int tx = threadIdx.x, ty = threadIdx.y;
#pragma unroll
  for (int i = 0; i < 4; ++i) {
    int r = r0 + ty + i * 8;
    u16 v;
    if (SRC_F32) v = f2bf(sf[(long)r * C + c0 + tx]);
    else         v = sh[(long)r * C + c0 + tx];
    tile[ty + i * 8][tx] = v;
  }
  __syncthreads();
#pragma unroll
  for (int i = 0; i < 4; ++i) {
    int rr = ty + i * 8;
    dst[(long)(c0 + rr) * R + r0 + tx] = tile[tx][rr];
  }
}

// ---------------- GEMM: C[m][n] = scale * sum_k A[m][k] * Bt[n][k] + bias[n] ------
// A: fp32 (AF32=true, reg-staged + cvt) or bf16 (global_load_lds). Bt: bf16.
// Tiles: BM=BN=128, BK=64. 256 threads = 4 waves (2x2), wave tile 64x64.
#define BM 128
#define BN 128
#define BK 64

struct GemmParams {
  const void* A;
  const u16* B;
  const float* bias;
  void* C;
  int M, N, K, lda, ldb, ldc;
  int div1, div2, out_bf16;
  long sA1, sA2, sB1, sB2, sC1, sC2;
  float scale;
};

template<bool AF32>
__global__ __launch_bounds__(256, 2)
void gemm_kernel(GemmParams p) {
  __shared__ __align__(16) u16 lds[2][2][BM * BK];  // [buf][A/B][...]
  const int t = threadIdx.x;
  const int w = t >> 6, l = t & 63;
  const int z = blockIdx.y;
  const int nTn = p.N / BN;
  const int tm = (blockIdx.x / nTn) * BM;
  const int tn = (blockIdx.x % nTn) * BN;
  const long offA = (long)(z / p.div1) * p.sA1 + (long)(z % p.div1) * p.sA2;
  const long offB = (long)(z / p.div1) * p.sB1 + (long)((z % p.div1) / p.div2) * p.sB2;
  const long offC = (long)(z / p.div1) * p.sC1 + (long)(z % p.div1) * p.sC2;

  const u16*   Ab = (const u16*)p.A + offA + (long)tm * p.lda;   // bf16 path
  const float* Af = (const float*)p.A + offA + (long)tm * p.lda; // f32 path
  const u16*   Bt = p.B + offB + (long)tn * p.ldb;

  const int wr = w >> 1, wc = w & 1;
  f32x4 acc[4][4] = {};
  float aR[32];  // f32-A staging registers (4 chunks x 8 floats)

  auto stageB = [&](int kt, int buf) {
    const u16* g0 = Bt + kt * BK;
#pragma unroll
    for (int i = 0; i < 4; ++i) {
      int c = i * 256 + t;
      int row = c >> 3;
      int slot = (c & 7) ^ (row & 7);
      const u16* gp = g0 + (long)row * p.ldb + slot * 8;
      u16* lp = &lds[buf][1][(i * 256 + w * 64) * 8];  // wave-uniform base
      __builtin_amdgcn_global_load_lds(
          (const __attribute__((address_space(1))) unsigned int*)gp,
          (__attribute__((address_space(3))) unsigned int*)lp, 16, 0, 0);
    }
  };
  auto stageA_bf16 = [&](int kt, int buf) {
    const u16* g0 = Ab + kt * BK;
#pragma unroll
    for (int i = 0; i < 4; ++i) {
      int c = i * 256 + t;
      int row = c >> 3;
      int slot = (c & 7) ^ (row & 7);
      const u16* gp = g0 + (long)row * p.lda + slot * 8;
      u16* lp = &lds[buf][0][(i * 256 + w * 64) * 8];
      __builtin_amdgcn_global_load_lds(
          (const __attribute__((address_space(1))) unsigned int*)gp,
          (__attribute__((address_space(3))) unsigned int*)lp, 16, 0, 0);
    }
  };
  auto loadA_f32 = [&](int kt) {
    const float* g0 = Af + kt * BK;
#pragma unroll
    for (int i = 0; i < 4; ++i) {
      int c = i * 256 + t;
      int row = c >> 3, slot = c & 7;
      const float4* gp = (const float4*)(g0 + (long)row * p.lda + slot * 8);
      float4 v0 = gp[0], v1 = gp[1];
      aR[i * 8 + 0] = v0.x; aR[i * 8 + 1] = v0.y; aR[i * 8 + 2] = v0.z; aR[i * 8 + 3] = v0.w;
      aR[i * 8 + 4] = v1.x; aR[i * 8 + 5] = v1.y; aR[i * 8 + 6] = v1.z; aR[i * 8 + 7] = v1.w;
    }
  };
  auto writeA = [&](int buf) {
#pragma unroll
    for (int i = 0; i < 4; ++i) {
      int c = i * 256 + t;
      int row = c >> 3, slot = c & 7;
      short8 o;
#pragma unroll
      for (int j = 0; j < 8; ++j) o[j] = (short)f2bf(aR[i * 8 + j]);
      *(short8*)&lds[buf][0][row * 64 + ((slot ^ (row & 7)) * 8)] = o;
    }
  };
  auto compute = [&](int buf) {
    const u16* At  = lds[buf][0];
    const u16* Btl = lds[buf][1];
#pragma unroll
    for (int ks = 0; ks < 2; ++ks) {
      short8 af[4], bfr[4];
#pragma unroll
      for (int mi = 0; mi < 4; ++mi) {
        int row = wr * 64 + mi * 16 + (l & 15);
        int slot = (ks * 4 + (l >> 4)) ^ (row & 7);
        af[mi] = *(const short8*)&At[row * 64 + slot * 8];
      }
#pragma unroll
      for (int ni = 0; ni < 4; ++ni) {
        int row = wc * 64 + ni * 16 + (l & 15);
        int slot = (ks * 4 + (l >> 4)) ^ (row & 7);
        bfr[ni] = *(const short8*)&Btl[row * 64 + slot * 8];
      }
#pragma unroll
      for (int mi = 0; mi < 4; ++mi)
#pragma unroll
        for (int ni = 0; ni < 4; ++ni)
          acc[mi][ni] = __builtin_amdgcn_mfma_f32_16x16x32_bf16(
              af[mi], bfr[ni], acc[mi][ni], 0, 0, 0);
    }
  };

  const int nkt = p.K / BK;
  // prologue: stage tile 0 into buf 0
  if (AF32) { loadA_f32(0); stageB(0, 0); writeA(0); }
  else      { stageA_bf16(0, 0); stageB(0, 0); }
  __syncthreads();

  int buf = 0;
  for (int kt = 0; kt < nkt; ++kt) {
    if (kt + 1 < nkt) {
      if (AF32) loadA_f32(kt + 1); else stageA_bf16(kt + 1, buf ^ 1);
      stageB(kt + 1, buf ^ 1);
    }
    compute(buf);
    if (AF32 && kt + 1 < nkt) writeA(buf ^ 1);  // loads overlapped with compute
    __syncthreads();
    buf ^= 1;
  }

  // epilogue
  const int cl = l & 15, rj = (l >> 4) * 4;
#pragma unroll
  for (int mi = 0; mi < 4; ++mi) {
#pragma unroll
    for (int ni = 0; ni < 4; ++ni) {
      int cidx = tn + wc * 64 + ni * 16 + cl;
      float bv = p.bias ? p.bias[cidx] : 0.f;
#pragma unroll
      for (int j = 0; j < 4; ++j) {
        int r = tm + wr * 64 + mi * 16 + rj + j;
        float v = acc[mi][ni][j] * p.scale + bv;
        long idx = offC + (long)r * p.ldc + cidx;
        if (p.out_bf16) ((u16*)p.C)[idx] = f2bf(v);
        else            ((float*)p.C)[idx] = v;
      }
    }
  }
}

// ---------------- in-place row softmax over 1024-wide rows ----------------
__global__ __launch_bounds__(256)
void softmax_kernel(float* attn) {
  const int w = threadIdx.x >> 6, l = threadIdx.x & 63;
  float* p = attn + ((long)blockIdx.x * 4 + w) * 1024;
  float4 v[4];
#pragma unroll
  for (int i = 0; i < 4; ++i) v[i] = *(const float4*)(p + i * 256 + l * 4);
  float m = -1e30f;
#pragma unroll
  for (int i = 0; i < 4; ++i)
    m = fmaxf(m, fmaxf(fmaxf(v[i].x, v[i].y), fmaxf(v[i].z, v[i].w)));
#pragma unroll
  for (int off = 32; off >= 1; off >>= 1) m = fmaxf(m, __shfl_xor(m, off));
  float s = 0.f;
#pragma unroll
  for (int i = 0; i < 4; ++i) {
    v[i].x = __expf(v[i].x - m); v[i].y = __expf(v[i].y - m);
    v[i].z = __expf(v[i].z - m); v[i].w = __expf(v[i].w - m);
    s += v[i].x + v[i].y + v[i].z + v[i].w;
  }
#pragma unroll
  for (int off = 32; off >= 1; off >>= 1) s += __shfl_xor(s, off);
  const float inv = 1.0f / s;
#pragma unroll
  for (int i = 0; i < 4; ++i) {
    v[i].x *= inv; v[i].y *= inv; v[i].z *= inv; v[i].w *= inv;
    *(float4*)(p + i * 256 + l * 4) = v[i];
  }
}

// ---------------- host ----------------
extern "C" void kernel_launch(void* const* d_in, const int* in_sizes, int n_in,
                              void* d_out, int out_size, void* d_ws, size_t ws_size,
                              hipStream_t stream) {
  const float* query = (const float*)d_in[0];
  const float* key_  = (const float*)d_in[1];
  const float* value = (const float*)d_in[2];
  const float* Wq = (const float*)d_in[3]; const float* bq = (const float*)d_in[4];
  const float* Wk = (const float*)d_in[5]; const float* bk = (const float*)d_in[6];
  const float* Wv = (const float*)d_in[7]; const float* bv = (const float*)d_in[8];
  const float* Wo = (const float*)d_in[9]; const float* bo = (const float*)d_in[10];

  float* outF  = (float*)d_out;                 // [4,1024,2048]
  float* attnF = outF + 8388608;                // [4,16,1024,1024]

  char* wp = (char*)d_ws;
  u16* WqT = (u16*)wp; wp += 2048L * 2048 * 2;
  u16* WkT = (u16*)wp; wp += 512L * 2048 * 2;
  u16* WvT = (u16*)wp; wp += 512L * 2048 * 2;
  u16* WoT = (u16*)wp; wp += 2048L * 2048 * 2;
  u16* Qb  = (u16*)wp; wp += 4096L * 2048 * 2;
  u16* Kb  = (u16*)wp; wp += 4096L * 512 * 2;
  u16* Vb  = (u16*)wp; wp += 4096L * 512 * 2;
  u16* VT  = (u16*)wp; wp += 4L * 512 * 1024 * 2;
  u16* AO  = (u16*)wp; wp += 4096L * 2048 * 2;

  dim3 tb(32, 8);
  // weight transposes: dst[N][K] = W[K][N]
  transpose_cvt_kernel<true><<<dim3(64, 64, 1), tb, 0, stream>>>(Wq, WqT, 2048, 2048, 0, 0);
  transpose_cvt_kernel<true><<<dim3(16, 64, 1), tb, 0, stream>>>(Wk, WkT, 2048, 512, 0, 0);
  transpose_cvt_kernel<true><<<dim3(16, 64, 1), tb, 0, stream>>>(Wv, WvT, 2048, 512, 0, 0);
  transpose_cvt_kernel<true><<<dim3(64, 64, 1), tb, 0, stream>>>(Wo, WoT, 2048, 2048, 0, 0);

  GemmParams gp;
  gp.div1 = 1; gp.div2 = 1;
  gp.sA1 = gp.sA2 = gp.sB1 = gp.sB2 = gp.sC1 = gp.sC2 = 0;
  gp.scale = 1.f;

  // Q projection: [4096,2048] x WqT -> Qb bf16
  gp.A = query; gp.B = WqT; gp.bias = bq; gp.C = Qb;
  gp.M = 4096; gp.N = 2048; gp.K = 2048; gp.lda = 2048; gp.ldb = 2048; gp.ldc = 2048;
  gp.out_bf16 = 1;
  gemm_kernel<true><<<dim3(512, 1), 256, 0, stream>>>(gp);

  // K projection -> Kb bf16 [4096,512]
  gp.A = key_; gp.B = WkT; gp.bias = bk; gp.C = Kb;
  gp.N = 512; gp.ldb = 2048; gp.ldc = 512;
  gemm_kernel<true><<<dim3(128, 1), 256, 0, stream>>>(gp);

  // V projection -> Vb bf16 [4096,512]
  gp.A = value; gp.B = WvT; gp.bias = bv; gp.C = Vb;
  gemm_kernel<true><<<dim3(128, 1), 256, 0, stream>>>(gp);

  // V transpose per batch: VT[b][512][1024] = Vb[b][1024][512]^T
  transpose_cvt_kernel<false><<<dim3(16, 32, 4), tb, 0, stream>>>(
      Vb, VT, 1024, 512, 1024L * 512, 512L * 1024);

  // scores: per (b,h): Qb slice [1024,128] x Kb slice -> attnF fp32, scaled
  gp.A = Qb; gp.B = Kb; gp.bias = nullptr; gp.C = attnF;
  gp.M = 1024; gp.N = 1024; gp.K = 128; gp.lda = 2048; gp.ldb = 512; gp.ldc = 1024;
  gp.div1 = 16; gp.div2 = 4;
  gp.sA1 = 2097152; gp.sA2 = 128;      // b*1024*2048 + h*128
  gp.sB1 = 524288;  gp.sB2 = 128;      // b*1024*512  + g*128
  gp.sC1 = 16777216; gp.sC2 = 1048576; // (b*16+h)*1024*1024
  gp.scale = 0.08838834764831845f;     // 1/sqrt(128)
  gp.out_bf16 = 0;
  gemm_kernel<false><<<dim3(64, 64), 256, 0, stream>>>(gp);

  // softmax in place: 65536 rows of 1024
  softmax_kernel<<<dim3(16384, 1), 256, 0, stream>>>(attnF);

  // PV: per (b,h): P fp32 [1024,1024] x VT[b][g] -> AO bf16 [B,S,D] slice
  gp.A = attnF; gp.B = VT; gp.bias = nullptr; gp.C = AO;
  gp.M = 1024; gp.N = 128; gp.K = 1024; gp.lda = 1024; gp.ldb = 1024; gp.ldc = 2048;
  gp.sA1 = 16777216; gp.sA2 = 1048576; // (b*16+h)*1M
  gp.sB1 = 524288;   gp.sB2 = 131072;  // b*512*1024 + g*128*1024
  gp.sC1 = 2097152;  gp.sC2 = 128;     // b*1024*2048 + h*128
  gp.scale = 1.f;
  gp.out_bf16 = 1;
  gemm_kernel<true><<<dim3(8, 64), 256, 0, stream>>>(gp);

  // O projection: AO [4096,2048] x WoT + bo -> outF fp32
  gp.A = AO; gp.B = WoT; gp.bias = bo; gp.C = outF;
  gp.M = 4096; gp.N = 2048; gp.K = 2048; gp.lda = 2048; gp.ldb = 2048; gp.ldc = 2048;
  gp.div1 = 1; gp.div2 = 1;
  gp.sA1 = gp.sA2 = gp.sB1 = gp.sB2 = gp.sC1 = gp.sC2 = 0;
  gp.scale = 1.f; gp.out_bf16 = 0;
  gemm_kernel<false><<<dim3(512, 1), 256, 0, stream>>>(gp);
}

// Round 3
// 394.533 us; speedup vs baseline: 1.2032x; 1.2032x over previous
//
#include <hip/hip_runtime.h>

typedef unsigned short u16;
typedef __attribute__((ext_vector_type(8))) short short8;
typedef __attribute__((ext_vector_type(4))) float f32x4;

__device__ __forceinline__ u16 f2bf(float f) {
  union { float f; unsigned u; } a; a.f = f;
  unsigned u = a.u;
  u += 0x7fffu + ((u >> 16) & 1u);
  return (u16)(u >> 16);
}

// ---------------- transpose + convert: dst[c][r] = (bf16)src[r][c] ----------------
template<bool SRC_F32>
__global__ __launch_bounds__(256)
void transpose_cvt_kernel(const void* src_, u16* dst, int R, int C,
                          long sbatch, long dbatch) {
  const int bz = blockIdx.z;
  const float* sf = (const float*)src_ + (long)bz * sbatch;
  const u16*   sh = (const u16*)src_ + (long)bz * sbatch;
  dst += (long)bz * dbatch;
  __shared__ u16 tile[32][33];
  const int c0 = blockIdx.x * 32, r0 = blockIdx.y * 32;
  const int tx = threadIdx.x, ty = threadIdx.y;
#pragma unroll
  for (int i = 0; i < 4; ++i) {
    int r = r0 + ty + i * 8;
    u16 v;
    if (SRC_F32) v = f2bf(sf[(long)r * C + c0 + tx]);
    else         v = sh[(long)r * C + c0 + tx];
    tile[ty + i * 8][tx] = v;
  }
  __syncthreads();
#pragma unroll
  for (int i = 0; i < 4; ++i) {
    int rr = ty + i * 8;
    dst[(long)(c0 + rr) * R + r0 + tx] = tile[tx][rr];
  }
}

// ---------------- GEMM: C[m][n] = scale * sum_k A[m][k] * Bt[n][k] + bias[n] ------
#define BM 128
#define BN 128
#define BK 64

struct GemmParams {
  const void* A;
  const u16* B;
  const float* bias;
  void* C;
  // second problem (z==1) when A2 != nullptr (offsets forced to 0)
  const void* A2;
  const u16* B2;
  const float* bias2;
  void* C2;
  int M, N, K, lda, ldb, ldc;
  int div1, div2, out_bf16;
  long sA1, sA2, sB1, sB2, sC1, sC2;
  float scale;
};

template<bool AF32>
__global__ __launch_bounds__(256, 2)
void gemm_kernel(GemmParams p) {
  __shared__ __align__(16) u16 lds[2][2][BM * BK];  // [buf][A/B][...]
  const int t = threadIdx.x;
  const int w = t >> 6, l = t & 63;
  const int z = blockIdx.y;
  const int nTn = p.N / BN;
  const int tm = (blockIdx.x / nTn) * BM;
  const int tn = (blockIdx.x % nTn) * BN;

  const void* Asel = p.A; const u16* Bsel = p.B;
  void* Csel = p.C; const float* biasSel = p.bias;
  long offA = (long)(z / p.div1) * p.sA1 + (long)(z % p.div1) * p.sA2;
  long offB = (long)(z / p.div1) * p.sB1 + (long)((z % p.div1) / p.div2) * p.sB2;
  long offC = (long)(z / p.div1) * p.sC1 + (long)(z % p.div1) * p.sC2;
  if (p.A2) {
    offA = offB = offC = 0;
    if (z) { Asel = p.A2; Bsel = p.B2; Csel = p.C2; biasSel = p.bias2; }
  }

  const u16*   Ab = (const u16*)Asel + offA + (long)tm * p.lda;   // bf16 path
  const float* Af = (const float*)Asel + offA + (long)tm * p.lda; // f32 path
  const u16*   Bt = Bsel + offB + (long)tn * p.ldb;

  const int wr = w >> 1, wc = w & 1;
  f32x4 acc[4][4] = {};
  float aR[32];

  auto stageB = [&](int kt, int buf) {
    const u16* g0 = Bt + kt * BK;
#pragma unroll
    for (int i = 0; i < 4; ++i) {
      int c = i * 256 + t;
      int row = c >> 3;
      int slot = (c & 7) ^ (row & 7);
      const u16* gp = g0 + (long)row * p.ldb + slot * 8;
      u16* lp = &lds[buf][1][(i * 256 + w * 64) * 8];
      __builtin_amdgcn_global_load_lds(
          (const __attribute__((address_space(1))) unsigned int*)gp,
          (__attribute__((address_space(3))) unsigned int*)lp, 16, 0, 0);
    }
  };
  auto stageA_bf16 = [&](int kt, int buf) {
    const u16* g0 = Ab + kt * BK;
#pragma unroll
    for (int i = 0; i < 4; ++i) {
      int c = i * 256 + t;
      int row = c >> 3;
      int slot = (c & 7) ^ (row & 7);
      const u16* gp = g0 + (long)row * p.lda + slot * 8;
      u16* lp = &lds[buf][0][(i * 256 + w * 64) * 8];
      __builtin_amdgcn_global_load_lds(
          (const __attribute__((address_space(1))) unsigned int*)gp,
          (__attribute__((address_space(3))) unsigned int*)lp, 16, 0, 0);
    }
  };
  auto loadA_f32 = [&](int kt) {
    const float* g0 = Af + kt * BK;
#pragma unroll
    for (int i = 0; i < 4; ++i) {
      int c = i * 256 + t;
      int row = c >> 3, slot = c & 7;
      const float4* gp = (const float4*)(g0 + (long)row * p.lda + slot * 8);
      float4 v0 = gp[0], v1 = gp[1];
      aR[i * 8 + 0] = v0.x; aR[i * 8 + 1] = v0.y; aR[i * 8 + 2] = v0.z; aR[i * 8 + 3] = v0.w;
      aR[i * 8 + 4] = v1.x; aR[i * 8 + 5] = v1.y; aR[i * 8 + 6] = v1.z; aR[i * 8 + 7] = v1.w;
    }
  };
  auto writeA = [&](int buf) {
#pragma unroll
    for (int i = 0; i < 4; ++i) {
      int c = i * 256 + t;
      int row = c >> 3, slot = c & 7;
      short8 o;
#pragma unroll
      for (int j = 0; j < 8; ++j) o[j] = (short)f2bf(aR[i * 8 + j]);
      *(short8*)&lds[buf][0][row * 64 + ((slot ^ (row & 7)) * 8)] = o;
    }
  };
  auto compute = [&](int buf) {
    const u16* At  = lds[buf][0];
    const u16* Btl = lds[buf][1];
#pragma unroll
    for (int ks = 0; ks < 2; ++ks) {
      short8 af[4], bfr[4];
#pragma unroll
      for (int mi = 0; mi < 4; ++mi) {
        int row = wr * 64 + mi * 16 + (l & 15);
        int slot = (ks * 4 + (l >> 4)) ^ (row & 7);
        af[mi] = *(const short8*)&At[row * 64 + slot * 8];
      }
#pragma unroll
      for (int ni = 0; ni < 4; ++ni) {
        int row = wc * 64 + ni * 16 + (l & 15);
        int slot = (ks * 4 + (l >> 4)) ^ (row & 7);
        bfr[ni] = *(const short8*)&Btl[row * 64 + slot * 8];
      }
#pragma unroll
      for (int mi = 0; mi < 4; ++mi)
#pragma unroll
        for (int ni = 0; ni < 4; ++ni)
          acc[mi][ni] = __builtin_amdgcn_mfma_f32_16x16x32_bf16(
              af[mi], bfr[ni], acc[mi][ni], 0, 0, 0);
    }
  };

  const int nkt = p.K / BK;
  if (AF32) { loadA_f32(0); stageB(0, 0); writeA(0); }
  else      { stageA_bf16(0, 0); stageB(0, 0); }
  __syncthreads();

  int buf = 0;
  for (int kt = 0; kt < nkt; ++kt) {
    if (kt + 1 < nkt) {
      if (AF32) loadA_f32(kt + 1); else stageA_bf16(kt + 1, buf ^ 1);
      stageB(kt + 1, buf ^ 1);
    }
    compute(buf);
    if (AF32 && kt + 1 < nkt) writeA(buf ^ 1);
    __syncthreads();
    buf ^= 1;
  }

  const int cl = l & 15, rj = (l >> 4) * 4;
#pragma unroll
  for (int mi = 0; mi < 4; ++mi) {
#pragma unroll
    for (int ni = 0; ni < 4; ++ni) {
      int cidx = tn + wc * 64 + ni * 16 + cl;
      float bv = biasSel ? biasSel[cidx] : 0.f;
#pragma unroll
      for (int j = 0; j < 4; ++j) {
        int r = tm + wr * 64 + mi * 16 + rj + j;
        float v = acc[mi][ni][j] * p.scale + bv;
        long idx = offC + (long)r * p.ldc + cidx;
        if (p.out_bf16) ((u16*)Csel)[idx] = f2bf(v);
        else            ((float*)Csel)[idx] = v;
      }
    }
  }
}

// ---------------- fused scores -> softmax -> PV ----------------
// grid (32 qblocks, 64 b*h), 512 threads = 8 waves: wave = (wq in 0..1, wcol in 0..3)
// Per block: Q rows q0..q0+31, all 1024 cols. K/V streamed in 8 x [128][128] chunks.
__global__ __launch_bounds__(512, 1)
void fused_attn_kernel(const u16* __restrict__ Qg, const u16* __restrict__ Kg,
                       const u16* __restrict__ Vg, float* __restrict__ attnF,
                       u16* __restrict__ AO) {
  __shared__ __align__(16) u16 kv[2][128 * 128];   // 2 x 32 KB, swizzled slots
  __shared__ __align__(16) u16 p_lds[32 * 1032];   // 66 KB (also used for Q stage)
  __shared__ float red[2][4][32];

  const int t = threadIdx.x;
  const int w = t >> 6, l = t & 63;
  const int wq = w >> 2, wcol = w & 3;
  const int qb = blockIdx.x, z = blockIdx.y;
  const int b = z >> 4, h = z & 15, g = h >> 2;
  const int q0 = qb * 32;

  const u16* Qbase = Qg + ((long)b * 1024 + q0) * 2048 + h * 128;
  const u16* Kbase = Kg + (long)b * 1024 * 512 + g * 128;
  const u16* Vbase = Vg + ((long)b * 512 + g * 128) * 1024;  // VT rows=d, cols=s
  float* attnO = attnF + ((long)z * 1024 + q0) * 1024;

  auto stageK = [&](int c, int buf) {
#pragma unroll
    for (int i = 0; i < 4; ++i) {
      int idx = i * 512 + t;
      int row = idx >> 4, slot = idx & 15;
      const u16* gp = Kbase + (long)(c * 128 + row) * 512 + ((slot ^ (row & 15)) * 8);
      u16* lp = &kv[buf][(i * 512 + w * 64) * 8];
      __builtin_amdgcn_global_load_lds(
          (const __attribute__((address_space(1))) unsigned int*)gp,
          (__attribute__((address_space(3))) unsigned int*)lp, 16, 0, 0);
    }
  };
  auto stageV = [&](int sc, int buf) {
#pragma unroll
    for (int i = 0; i < 4; ++i) {
      int idx = i * 512 + t;
      int row = idx >> 4, slot = idx & 15;
      const u16* gp = Vbase + (long)row * 1024 + sc * 128 + ((slot ^ (row & 15)) * 8);
      u16* lp = &kv[buf][(i * 512 + w * 64) * 8];
      __builtin_amdgcn_global_load_lds(
          (const __attribute__((address_space(1))) unsigned int*)gp,
          (__attribute__((address_space(3))) unsigned int*)lp, 16, 0, 0);
    }
  };

  // stage Q [32][128] into p_lds (swizzled), plus K chunk 0
  {
    int row = t >> 4, slot = t & 15;
    const u16* gp = Qbase + (long)row * 2048 + ((slot ^ (row & 15)) * 8);
    u16* lp = &p_lds[(w * 64) * 8];
    __builtin_amdgcn_global_load_lds(
        (const __attribute__((address_space(1))) unsigned int*)gp,
        (__attribute__((address_space(3))) unsigned int*)lp, 16, 0, 0);
  }
  stageK(0, 0);
  __syncthreads();

  // Q fragments to registers: rows wq*16 + (l&15)
  short8 qf[4];
  {
    int row = wq * 16 + (l & 15);
#pragma unroll
    for (int ks = 0; ks < 4; ++ks) {
      int slot = (ks * 4 + (l >> 4)) ^ (row & 15);
      qf[ks] = *(const short8*)&p_lds[row * 128 + slot * 8];
    }
  }

  // ---- scores: acc[c][ni] covers cols c*128 + wcol*32 + ni*16 + (l&15)
  f32x4 acc[8][2] = {};
#pragma unroll
  for (int c = 0; c < 8; ++c) {
    if (c < 7) stageK(c + 1, (c + 1) & 1);
    else       stageV(0, 0);  // overlap V chunk0 with last compute + softmax
    const u16* Kl = kv[c & 1];
#pragma unroll
    for (int ks = 0; ks < 4; ++ks) {
      short8 bf0, bf1;
      {
        int row = wcol * 32 + (l & 15);
        int slot = (ks * 4 + (l >> 4)) ^ (row & 15);
        bf0 = *(const short8*)&Kl[row * 128 + slot * 8];
      }
      {
        int row = wcol * 32 + 16 + (l & 15);
        int slot = (ks * 4 + (l >> 4)) ^ (row & 15);
        bf1 = *(const short8*)&Kl[row * 128 + slot * 8];
      }
      acc[c][0] = __builtin_amdgcn_mfma_f32_16x16x32_bf16(qf[ks], bf0, acc[c][0], 0, 0, 0);
      acc[c][1] = __builtin_amdgcn_mfma_f32_16x16x32_bf16(qf[ks], bf1, acc[c][1], 0, 0, 0);
    }
    __syncthreads();
  }

  // ---- softmax over 1024 cols per row; lane holds 16 cols of rows wq*16+(l>>4)*4+j
  const float scale = 0.08838834764831845f;
  const int r_lo = (l >> 4) * 4;
  float m[4], inv[4];
#pragma unroll
  for (int j = 0; j < 4; ++j) {
    float mx = -1e30f;
#pragma unroll
    for (int c = 0; c < 8; ++c) {
      mx = fmaxf(mx, fmaxf(acc[c][0][j], acc[c][1][j]));
    }
    mx = fmaxf(mx, __shfl_xor(mx, 1));
    mx = fmaxf(mx, __shfl_xor(mx, 2));
    mx = fmaxf(mx, __shfl_xor(mx, 4));
    mx = fmaxf(mx, __shfl_xor(mx, 8));
    m[j] = mx;
  }
  if ((l & 15) == 0) {
#pragma unroll
    for (int j = 0; j < 4; ++j) red[0][wcol][wq * 16 + r_lo + j] = m[j];
  }
  __syncthreads();
#pragma unroll
  for (int j = 0; j < 4; ++j) {
    int r = wq * 16 + r_lo + j;
    m[j] = fmaxf(fmaxf(red[0][0][r], red[0][1][r]), fmaxf(red[0][2][r], red[0][3][r]));
  }
  // exponentiate + partial sums
#pragma unroll
  for (int j = 0; j < 4; ++j) {
    float s = 0.f;
#pragma unroll
    for (int c = 0; c < 8; ++c) {
#pragma unroll
      for (int ni = 0; ni < 2; ++ni) {
        float e = __expf((acc[c][ni][j] - m[j]) * scale);
        acc[c][ni][j] = e;
        s += e;
      }
    }
    s += __shfl_xor(s, 1);
    s += __shfl_xor(s, 2);
    s += __shfl_xor(s, 4);
    s += __shfl_xor(s, 8);
    inv[j] = s;
  }
  if ((l & 15) == 0) {
#pragma unroll
    for (int j = 0; j < 4; ++j) red[1][wcol][wq * 16 + r_lo + j] = inv[j];
  }
  __syncthreads();
#pragma unroll
  for (int j = 0; j < 4; ++j) {
    int r = wq * 16 + r_lo + j;
    inv[j] = 1.0f / (red[1][0][r] + red[1][1][r] + red[1][2][r] + red[1][3][r]);
  }

  // ---- write normalized attn (fp32, output) + P (bf16) to LDS
#pragma unroll
  for (int c = 0; c < 8; ++c) {
#pragma unroll
    for (int ni = 0; ni < 2; ++ni) {
      int col = c * 128 + wcol * 32 + ni * 16 + (l & 15);
#pragma unroll
      for (int j = 0; j < 4; ++j) {
        int r = wq * 16 + r_lo + j;
        float v = acc[c][ni][j] * inv[j];
        attnO[(long)r * 1024 + col] = v;
        p_lds[r * 1032 + col] = f2bf(v);
      }
    }
  }
  __syncthreads();  // P ready; V chunk0 drained

  // ---- PV: O[32][128] = P[32][1024] x V^T; wave (wq,wd=wcol) does rows wq*16, cols wd*32
  f32x4 acc2[2] = {};
#pragma unroll
  for (int sc = 0; sc < 8; ++sc) {
    if (sc < 7) stageV(sc + 1, (sc + 1) & 1);
    const u16* Vl = kv[sc & 1];
    const int prow = wq * 16 + (l & 15);
#pragma unroll
    for (int ks = 0; ks < 4; ++ks) {
      short8 af = *(const short8*)&p_lds[prow * 1032 + sc * 128 + ks * 32 + ((l >> 4) * 8)];
#pragma unroll
      for (int ni = 0; ni < 2; ++ni) {
        int vrow = wcol * 32 + ni * 16 + (l & 15);
        int slot = (ks * 4 + (l >> 4)) ^ (vrow & 15);
        short8 bf = *(const short8*)&Vl[vrow * 128 + slot * 8];
        acc2[ni] = __builtin_amdgcn_mfma_f32_16x16x32_bf16(af, bf, acc2[ni], 0, 0, 0);
      }
    }
    __syncthreads();
  }

  // ---- write AO (bf16)
  u16* AObase = AO + ((long)b * 1024 + q0) * 2048 + h * 128;
#pragma unroll
  for (int ni = 0; ni < 2; ++ni) {
#pragma unroll
    for (int j = 0; j < 4; ++j) {
      int q = wq * 16 + r_lo + j;
      int d = wcol * 32 + ni * 16 + (l & 15);
      AObase[(long)q * 2048 + d] = f2bf(acc2[ni][j]);
    }
  }
}

// ---------------- host ----------------
extern "C" void kernel_launch(void* const* d_in, const int* in_sizes, int n_in,
                              void* d_out, int out_size, void* d_ws, size_t ws_size,
                              hipStream_t stream) {
  const float* query = (const float*)d_in[0];
  const float* key_  = (const float*)d_in[1];
  const float* value = (const float*)d_in[2];
  const float* Wq = (const float*)d_in[3]; const float* bq = (const float*)d_in[4];
  const float* Wk = (const float*)d_in[5]; const float* bk = (const float*)d_in[6];
  const float* Wv = (const float*)d_in[7]; const float* bv = (const float*)d_in[8];
  const float* Wo = (const float*)d_in[9]; const float* bo = (const float*)d_in[10];

  float* outF  = (float*)d_out;                 // [4,1024,2048]
  float* attnF = outF + 8388608;                // [4,16,1024,1024]

  char* wp = (char*)d_ws;
  u16* WqT = (u16*)wp; wp += 2048L * 2048 * 2;
  u16* WkT = (u16*)wp; wp += 512L * 2048 * 2;
  u16* WvT = (u16*)wp; wp += 512L * 2048 * 2;
  u16* WoT = (u16*)wp; wp += 2048L * 2048 * 2;
  u16* Qb  = (u16*)wp; wp += 4096L * 2048 * 2;
  u16* Kb  = (u16*)wp; wp += 4096L * 512 * 2;
  u16* Vb  = (u16*)wp; wp += 4096L * 512 * 2;
  u16* VT  = (u16*)wp; wp += 4L * 512 * 1024 * 2;
  u16* AO  = (u16*)wp; wp += 4096L * 2048 * 2;

  dim3 tb(32, 8);
  transpose_cvt_kernel<true><<<dim3(64, 64, 1), tb, 0, stream>>>(Wq, WqT, 2048, 2048, 0, 0);
  transpose_cvt_kernel<true><<<dim3(16, 64, 1), tb, 0, stream>>>(Wk, WkT, 2048, 512, 0, 0);
  transpose_cvt_kernel<true><<<dim3(16, 64, 1), tb, 0, stream>>>(Wv, WvT, 2048, 512, 0, 0);
  transpose_cvt_kernel<true><<<dim3(64, 64, 1), tb, 0, stream>>>(Wo, WoT, 2048, 2048, 0, 0);

  GemmParams gp = {};
  gp.div1 = 1; gp.div2 = 1;
  gp.sA1 = gp.sA2 = gp.sB1 = gp.sB2 = gp.sC1 = gp.sC2 = 0;
  gp.scale = 1.f;

  // Q projection: [4096,2048] x WqT -> Qb bf16
  gp.A = query; gp.B = WqT; gp.bias = bq; gp.C = Qb;
  gp.M = 4096; gp.N = 2048; gp.K = 2048; gp.lda = 2048; gp.ldb = 2048; gp.ldc = 2048;
  gp.out_bf16 = 1;
  gemm_kernel<true><<<dim3(512, 1), 256, 0, stream>>>(gp);

  // K + V projections fused across blockIdx.y: z=0 -> K, z=1 -> V
  gp.A = key_;  gp.B = WkT; gp.bias = bk; gp.C = Kb;
  gp.A2 = value; gp.B2 = WvT; gp.bias2 = bv; gp.C2 = Vb;
  gp.N = 512; gp.ldb = 2048; gp.ldc = 512;
  gemm_kernel<true><<<dim3(128, 2), 256, 0, stream>>>(gp);
  gp.A2 = nullptr; gp.B2 = nullptr; gp.bias2 = nullptr; gp.C2 = nullptr;

  // V transpose per batch: VT[b][512][1024] = Vb[b][1024][512]^T
  transpose_cvt_kernel<false><<<dim3(16, 32, 4), tb, 0, stream>>>(
      Vb, VT, 1024, 512, 1024L * 512, 512L * 1024);

  // fused scores/softmax/PV: grid (qblocks=32, bh=64)
  fused_attn_kernel<<<dim3(32, 64), 512, 0, stream>>>(Qb, Kb, VT, attnF, AO);

  // O projection: AO [4096,2048] x WoT + bo -> outF fp32
  gp.A = AO; gp.B = WoT; gp.bias = bo; gp.C = outF;
  gp.M = 4096; gp.N = 2048; gp.K = 2048; gp.lda = 2048; gp.ldb = 2048; gp.ldc = 2048;
  gp.scale = 1.f; gp.out_bf16 = 0;
  gemm_kernel<false><<<dim3(512, 1), 256, 0, stream>>>(gp);
}

// Round 4
// 359.274 us; speedup vs baseline: 1.3213x; 1.0981x over previous
//
#include <hip/hip_runtime.h>

typedef unsigned short u16;
typedef __attribute__((ext_vector_type(8))) short short8;
typedef __attribute__((ext_vector_type(4))) float f32x4;

__device__ __forceinline__ u16 f2bf(float f) {
  union { float f; unsigned u; } a; a.f = f;
  unsigned u = a.u;
  u += 0x7fffu + ((u >> 16) & 1u);
  return (u16)(u >> 16);
}

// ---------------- transpose + convert: dst[c][r] = (bf16)src[r][c] ----------------
template<bool SRC_F32>
__global__ __launch_bounds__(256)
void transpose_cvt_kernel(const void* src_, u16* dst, int R, int C,
                          long sbatch, long dbatch) {
  const int bz = blockIdx.z;
  const float* sf = (const float*)src_ + (long)bz * sbatch;
  const u16*   sh = (const u16*)src_ + (long)bz * sbatch;
  dst += (long)bz * dbatch;
  __shared__ u16 tile[32][33];
  const int c0 = blockIdx.x * 32, r0 = blockIdx.y * 32;
  const int tx = threadIdx.x, ty = threadIdx.y;
#pragma unroll
  for (int i = 0; i < 4; ++i) {
    int r = r0 + ty + i * 8;
    u16 v;
    if (SRC_F32) v = f2bf(sf[(long)r * C + c0 + tx]);
    else         v = sh[(long)r * C + c0 + tx];
    tile[ty + i * 8][tx] = v;
  }
  __syncthreads();
#pragma unroll
  for (int i = 0; i < 4; ++i) {
    int rr = ty + i * 8;
    dst[(long)(c0 + rr) * R + r0 + tx] = tile[tx][rr];
  }
}

// ---------------- GEMM: C[m][n] = scale * sum_k A[m][k] * Bt[n][k] + bias[n] ------
#define BM 128
#define BN 128
#define BK 64

struct GemmParams {
  const void* A;
  const u16* B;
  const float* bias;
  void* C;
  const void* A2;
  const u16* B2;
  const float* bias2;
  void* C2;
  int M, N, K, lda, ldb, ldc;
  int div1, div2, out_bf16;
  long sA1, sA2, sB1, sB2, sC1, sC2;
  float scale;
};

template<bool AF32>
__global__ __launch_bounds__(256, 2)
void gemm_kernel(GemmParams p) {
  __shared__ __align__(16) u16 lds[2][2][BM * BK];
  const int t = threadIdx.x;
  const int w = t >> 6, l = t & 63;
  const int z = blockIdx.y;
  const int nTn = p.N / BN;
  const int tm = (blockIdx.x / nTn) * BM;
  const int tn = (blockIdx.x % nTn) * BN;

  const void* Asel = p.A; const u16* Bsel = p.B;
  void* Csel = p.C; const float* biasSel = p.bias;
  long offA = (long)(z / p.div1) * p.sA1 + (long)(z % p.div1) * p.sA2;
  long offB = (long)(z / p.div1) * p.sB1 + (long)((z % p.div1) / p.div2) * p.sB2;
  long offC = (long)(z / p.div1) * p.sC1 + (long)(z % p.div1) * p.sC2;
  if (p.A2) {
    offA = offB = offC = 0;
    if (z) { Asel = p.A2; Bsel = p.B2; Csel = p.C2; biasSel = p.bias2; }
  }

  const u16*   Ab = (const u16*)Asel + offA + (long)tm * p.lda;
  const float* Af = (const float*)Asel + offA + (long)tm * p.lda;
  const u16*   Bt = Bsel + offB + (long)tn * p.ldb;

  const int wr = w >> 1, wc = w & 1;
  f32x4 acc[4][4] = {};
  float aR[32];

  auto stageB = [&](int kt, int buf) {
#pragma unroll
    for (int i = 0; i < 4; ++i) {
      int c = i * 256 + t;
      int row = c >> 3;
      int slot = (c & 7) ^ (row & 7);
      const u16* gp = Bt + kt * BK + (long)row * p.ldb + slot * 8;
      u16* lp = &lds[buf][1][(i * 256 + w * 64) * 8];
      __builtin_amdgcn_global_load_lds(
          (const __attribute__((address_space(1))) unsigned int*)gp,
          (__attribute__((address_space(3))) unsigned int*)lp, 16, 0, 0);
    }
  };
  auto stageA_bf16 = [&](int kt, int buf) {
#pragma unroll
    for (int i = 0; i < 4; ++i) {
      int c = i * 256 + t;
      int row = c >> 3;
      int slot = (c & 7) ^ (row & 7);
      const u16* gp = Ab + kt * BK + (long)row * p.lda + slot * 8;
      u16* lp = &lds[buf][0][(i * 256 + w * 64) * 8];
      __builtin_amdgcn_global_load_lds(
          (const __attribute__((address_space(1))) unsigned int*)gp,
          (__attribute__((address_space(3))) unsigned int*)lp, 16, 0, 0);
    }
  };
  auto loadA_f32 = [&](int kt) {
    const float* g0 = Af + kt * BK;
#pragma unroll
    for (int i = 0; i < 4; ++i) {
      int c = i * 256 + t;
      int row = c >> 3, slot = c & 7;
      const float4* gp = (const float4*)(g0 + (long)row * p.lda + slot * 8);
      float4 v0 = gp[0], v1 = gp[1];
      aR[i * 8 + 0] = v0.x; aR[i * 8 + 1] = v0.y; aR[i * 8 + 2] = v0.z; aR[i * 8 + 3] = v0.w;
      aR[i * 8 + 4] = v1.x; aR[i * 8 + 5] = v1.y; aR[i * 8 + 6] = v1.z; aR[i * 8 + 7] = v1.w;
    }
  };
  auto writeA = [&](int buf) {
#pragma unroll
    for (int i = 0; i < 4; ++i) {
      int c = i * 256 + t;
      int row = c >> 3, slot = c & 7;
      short8 o;
#pragma unroll
      for (int j = 0; j < 8; ++j) o[j] = (short)f2bf(aR[i * 8 + j]);
      *(short8*)&lds[buf][0][row * 64 + ((slot ^ (row & 7)) * 8)] = o;
    }
  };
  auto compute = [&](int buf) {
    const u16* At  = lds[buf][0];
    const u16* Btl = lds[buf][1];
#pragma unroll
    for (int ks = 0; ks < 2; ++ks) {
      short8 af[4], bfr[4];
#pragma unroll
      for (int mi = 0; mi < 4; ++mi) {
        int row = wr * 64 + mi * 16 + (l & 15);
        int slot = (ks * 4 + (l >> 4)) ^ (row & 7);
        af[mi] = *(const short8*)&At[row * 64 + slot * 8];
      }
#pragma unroll
      for (int ni = 0; ni < 4; ++ni) {
        int row = wc * 64 + ni * 16 + (l & 15);
        int slot = (ks * 4 + (l >> 4)) ^ (row & 7);
        bfr[ni] = *(const short8*)&Btl[row * 64 + slot * 8];
      }
#pragma unroll
      for (int mi = 0; mi < 4; ++mi)
#pragma unroll
        for (int ni = 0; ni < 4; ++ni)
          acc[mi][ni] = __builtin_amdgcn_mfma_f32_16x16x32_bf16(
              af[mi], bfr[ni], acc[mi][ni], 0, 0, 0);
    }
  };

  const int nkt = p.K / BK;
  if (AF32) { loadA_f32(0); stageB(0, 0); writeA(0); }
  else      { stageA_bf16(0, 0); stageB(0, 0); }
  __syncthreads();

  int buf = 0;
  for (int kt = 0; kt < nkt; ++kt) {
    if (kt + 1 < nkt) {
      if (AF32) loadA_f32(kt + 1); else stageA_bf16(kt + 1, buf ^ 1);
      stageB(kt + 1, buf ^ 1);
    }
    compute(buf);
    if (AF32 && kt + 1 < nkt) writeA(buf ^ 1);
    __syncthreads();
    buf ^= 1;
  }

  const int cl = l & 15, rj = (l >> 4) * 4;
#pragma unroll
  for (int mi = 0; mi < 4; ++mi) {
#pragma unroll
    for (int ni = 0; ni < 4; ++ni) {
      int cidx = tn + wc * 64 + ni * 16 + cl;
      float bv = biasSel ? biasSel[cidx] : 0.f;
#pragma unroll
      for (int j = 0; j < 4; ++j) {
        int r = tm + wr * 64 + mi * 16 + rj + j;
        float v = acc[mi][ni][j] * p.scale + bv;
        long idx = offC + (long)r * p.ldc + cidx;
        if (p.out_bf16) ((u16*)Csel)[idx] = f2bf(v);
        else            ((float*)Csel)[idx] = v;
      }
    }
  }
}

// ---------------- fused scores -> softmax -> PV (counted-vmcnt pipeline) ----------
// grid (32 qblocks, 64 b*h), 512 threads = 8 waves (wq 0..1, wcol 0..3).
// Chunk stream: c=0..15 K chunks [64 s][128 d], c=16..31 V chunks [128 d][64 s].
// Per stage: exactly 2 global_load_lds per thread -> static vmcnt counting.
__global__ __launch_bounds__(512, 2)
void fused_attn_kernel(const u16* __restrict__ Qg, const u16* __restrict__ Kg,
                       const u16* __restrict__ Vg, float* __restrict__ attnF,
                       u16* __restrict__ AO) {
  __shared__ __align__(16) u16 kv[2][64 * 128];    // 2 x 16 KB
  __shared__ __align__(16) u16 p_lds[32 * 1024];   // 64 KB, XOR-swizzled (Q stage first)
  __shared__ float red[2][4][32];

  const int t = threadIdx.x;
  const int w = t >> 6, l = t & 63;
  const int wq = w >> 2, wcol = w & 3;
  const int qb = blockIdx.x, z = blockIdx.y;
  const int b = z >> 4, h = z & 15, g = h >> 2;
  const int q0 = qb * 32;

  const u16* Qbase = Qg + ((long)b * 1024 + q0) * 2048 + h * 128;
  const u16* Kbase = Kg + (long)b * 1024 * 512 + g * 128;
  const u16* Vbase = Vg + ((long)b * 512 + g * 128) * 1024;  // VT: rows=d, cols=s
  float* attnO = attnF + ((long)z * 1024 + q0) * 1024;

  auto glds16 = [](const u16* gp, u16* lp) {
    __builtin_amdgcn_global_load_lds(
        (const __attribute__((address_space(1))) unsigned int*)gp,
        (__attribute__((address_space(3))) unsigned int*)lp, 16, 0, 0);
  };

  auto stageK = [&](int c, int buf) {       // chunk [64 rows(s)][128 cols(d)]
#pragma unroll
    for (int i = 0; i < 2; ++i) {
      int idx = i * 512 + t;
      int row = idx >> 4, blk = idx & 15;
      glds16(Kbase + (long)(c * 64 + row) * 512 + ((blk ^ (row & 7)) * 8),
             &kv[buf][(i * 512 + w * 64) * 8]);
    }
  };
  auto stageV = [&](int c, int buf) {       // chunk [128 rows(d)][64 cols(s)]
#pragma unroll
    for (int i = 0; i < 2; ++i) {
      int idx = i * 512 + t;
      int row = idx >> 3, blk = idx & 7;
      glds16(Vbase + (long)row * 1024 + c * 64 + ((blk ^ (row & 7)) * 8),
             &kv[buf][(i * 512 + w * 64) * 8]);
    }
  };

  // prologue: Q (1 load/thread) + K0 + K1 (2 each)
  {
    int row = t >> 4, blk = t & 15;
    glds16(Qbase + (long)row * 2048 + ((blk ^ (row & 7)) * 8), &p_lds[(w * 64) * 8]);
  }
  stageK(0, 0);
  stageK(1, 1);
  asm volatile("s_waitcnt vmcnt(2)" ::: "memory");   // Q + K0 done, K1 in flight
  __builtin_amdgcn_sched_barrier(0);
  __builtin_amdgcn_s_barrier();

  short8 qf[4];
  {
    int row = wq * 16 + (l & 15);
#pragma unroll
    for (int ks = 0; ks < 4; ++ks) {
      int slot = (ks * 4 + (l >> 4)) ^ (row & 7);
      qf[ks] = *(const short8*)&p_lds[row * 128 + slot * 8];
    }
  }

  f32x4 acc[16];
#pragma unroll
  for (int c = 0; c < 16; ++c) acc[c] = (f32x4){0.f, 0.f, 0.f, 0.f};

  // ---- scores loop: compute K chunk c, keep 2 stages in flight
  const int krow = wcol * 16 + (l & 15);
#pragma unroll
  for (int c = 0; c < 16; ++c) {
    const u16* Kl = kv[c & 1];
#pragma unroll
    for (int ks = 0; ks < 4; ++ks) {
      int slot = (ks * 4 + (l >> 4)) ^ (krow & 7);
      short8 kf = *(const short8*)&Kl[krow * 128 + slot * 8];
      acc[c] = __builtin_amdgcn_mfma_f32_16x16x32_bf16(qf[ks], kf, acc[c], 0, 0, 0);
    }
    __builtin_amdgcn_s_barrier();            // A: all done reading kv[c&1]
    if (c + 2 < 16) stageK(c + 2, c & 1);
    else            stageV(c + 2 - 16, c & 1);   // c=14 -> V0, c=15 -> V1
    asm volatile("s_waitcnt vmcnt(2)" ::: "memory");  // stage(c+1) arrived
    __builtin_amdgcn_sched_barrier(0);
    __builtin_amdgcn_s_barrier();            // B: kv[(c+1)&1] valid for all
  }

  // ---- softmax (rows q = wq*16 + (l>>4)*4 + j; 16 k-values per lane per row)
  const float scale = 0.08838834764831845f;  // 1/sqrt(128)
  const int r_lo = (l >> 4) * 4;
  float m4[4], inv4[4];
#pragma unroll
  for (int j = 0; j < 4; ++j) {
    float mx = -1e30f;
#pragma unroll
    for (int c = 0; c < 16; ++c) mx = fmaxf(mx, acc[c][j]);
    mx = fmaxf(mx, __shfl_xor(mx, 1));
    mx = fmaxf(mx, __shfl_xor(mx, 2));
    mx = fmaxf(mx, __shfl_xor(mx, 4));
    mx = fmaxf(mx, __shfl_xor(mx, 8));
    m4[j] = mx;
  }
  if ((l & 15) == 0) {
#pragma unroll
    for (int j = 0; j < 4; ++j) red[0][wcol][wq * 16 + r_lo + j] = m4[j];
  }
  __syncthreads();
#pragma unroll
  for (int j = 0; j < 4; ++j) {
    int r = wq * 16 + r_lo + j;
    m4[j] = fmaxf(fmaxf(red[0][0][r], red[0][1][r]), fmaxf(red[0][2][r], red[0][3][r]));
  }
#pragma unroll
  for (int j = 0; j < 4; ++j) {
    float s = 0.f;
#pragma unroll
    for (int c = 0; c < 16; ++c) {
      float e = __expf((acc[c][j] - m4[j]) * scale);
      acc[c][j] = e;
      s += e;
    }
    s += __shfl_xor(s, 1);
    s += __shfl_xor(s, 2);
    s += __shfl_xor(s, 4);
    s += __shfl_xor(s, 8);
    inv4[j] = s;
  }
  if ((l & 15) == 0) {
#pragma unroll
    for (int j = 0; j < 4; ++j) red[1][wcol][wq * 16 + r_lo + j] = inv4[j];
  }
  __syncthreads();
#pragma unroll
  for (int j = 0; j < 4; ++j) {
    int r = wq * 16 + r_lo + j;
    inv4[j] = 1.0f / (red[1][0][r] + red[1][1][r] + red[1][2][r] + red[1][3][r]);
  }

  // ---- write attn (f32, 64B runs) + P (bf16, swizzled) to p_lds
#pragma unroll
  for (int c = 0; c < 16; ++c) {
    int col = c * 64 + wcol * 16 + (l & 15);
    int blk_lo = wcol * 2 + ((l & 15) >> 3);
#pragma unroll
    for (int j = 0; j < 4; ++j) {
      int r = wq * 16 + r_lo + j;
      float v = acc[c][j] * inv4[j];
      attnO[(long)r * 1024 + col] = v;
      int pb = c * 8 + (blk_lo ^ (r & 7));
      p_lds[r * 1024 + pb * 8 + (col & 7)] = f2bf(v);
    }
  }
  __syncthreads();  // P visible; V0 already validated, V1 drained here

  // ---- PV: O[32 q][128 d]; wave (wq,wcol): q-rows wq*16, d-cols wcol*32
  f32x4 acc2[2] = {};
  const int prow = wq * 16 + (l & 15);
  for (int c2 = 0; c2 < 16; ++c2) {
    const u16* Vl = kv[c2 & 1];
#pragma unroll
    for (int ks = 0; ks < 2; ++ks) {
      int pb = c2 * 8 + ((ks * 4 + (l >> 4)) ^ (prow & 7));
      short8 af = *(const short8*)&p_lds[prow * 1024 + pb * 8];
#pragma unroll
      for (int ni = 0; ni < 2; ++ni) {
        int vrow = wcol * 32 + ni * 16 + (l & 15);
        int vslot = (ks * 4 + (l >> 4)) ^ (vrow & 7);
        short8 vf = *(const short8*)&Vl[vrow * 64 + vslot * 8];
        acc2[ni] = __builtin_amdgcn_mfma_f32_16x16x32_bf16(af, vf, acc2[ni], 0, 0, 0);
      }
    }
    if (c2 == 15) break;
    __builtin_amdgcn_s_barrier();            // A: done reading kv[c2&1]
    if (c2 + 2 < 16) {
      stageV(c2 + 2, c2 & 1);
      asm volatile("s_waitcnt vmcnt(2)" ::: "memory");
    } else {
      asm volatile("s_waitcnt vmcnt(0)" ::: "memory");
    }
    __builtin_amdgcn_sched_barrier(0);
    __builtin_amdgcn_s_barrier();            // B: kv[(c2+1)&1] valid
  }

  u16* AObase = AO + ((long)b * 1024 + q0) * 2048 + h * 128;
#pragma unroll
  for (int ni = 0; ni < 2; ++ni)
#pragma unroll
    for (int j = 0; j < 4; ++j) {
      int q = wq * 16 + r_lo + j;
      int d = wcol * 32 + ni * 16 + (l & 15);
      AObase[(long)q * 2048 + d] = f2bf(acc2[ni][j]);
    }
}

// ---------------- host ----------------
extern "C" void kernel_launch(void* const* d_in, const int* in_sizes, int n_in,
                              void* d_out, int out_size, void* d_ws, size_t ws_size,
                              hipStream_t stream) {
  const float* query = (const float*)d_in[0];
  const float* key_  = (const float*)d_in[1];
  const float* value = (const float*)d_in[2];
  const float* Wq = (const float*)d_in[3]; const float* bq = (const float*)d_in[4];
  const float* Wk = (const float*)d_in[5]; const float* bk = (const float*)d_in[6];
  const float* Wv = (const float*)d_in[7]; const float* bv = (const float*)d_in[8];
  const float* Wo = (const float*)d_in[9]; const float* bo = (const float*)d_in[10];

  float* outF  = (float*)d_out;                 // [4,1024,2048]
  float* attnF = outF + 8388608;                // [4,16,1024,1024]

  char* wp = (char*)d_ws;
  u16* WqT = (u16*)wp; wp += 2048L * 2048 * 2;
  u16* WkT = (u16*)wp; wp += 512L * 2048 * 2;
  u16* WvT = (u16*)wp; wp += 512L * 2048 * 2;
  u16* WoT = (u16*)wp; wp += 2048L * 2048 * 2;
  u16* Qb  = (u16*)wp; wp += 4096L * 2048 * 2;
  u16* Kb  = (u16*)wp; wp += 4096L * 512 * 2;
  u16* Vb  = (u16*)wp; wp += 4096L * 512 * 2;
  u16* VT  = (u16*)wp; wp += 4L * 512 * 1024 * 2;
  u16* AO  = (u16*)wp; wp += 4096L * 2048 * 2;

  dim3 tb(32, 8);
  transpose_cvt_kernel<true><<<dim3(64, 64, 1), tb, 0, stream>>>(Wq, WqT, 2048, 2048, 0, 0);
  transpose_cvt_kernel<true><<<dim3(16, 64, 1), tb, 0, stream>>>(Wk, WkT, 2048, 512, 0, 0);
  transpose_cvt_kernel<true><<<dim3(16, 64, 1), tb, 0, stream>>>(Wv, WvT, 2048, 512, 0, 0);
  transpose_cvt_kernel<true><<<dim3(64, 64, 1), tb, 0, stream>>>(Wo, WoT, 2048, 2048, 0, 0);

  GemmParams gp = {};
  gp.div1 = 1; gp.div2 = 1;
  gp.sA1 = gp.sA2 = gp.sB1 = gp.sB2 = gp.sC1 = gp.sC2 = 0;
  gp.scale = 1.f;

  // Q projection: [4096,2048] x WqT -> Qb bf16
  gp.A = query; gp.B = WqT; gp.bias = bq; gp.C = Qb;
  gp.M = 4096; gp.N = 2048; gp.K = 2048; gp.lda = 2048; gp.ldb = 2048; gp.ldc = 2048;
  gp.out_bf16 = 1;
  gemm_kernel<true><<<dim3(512, 1), 256, 0, stream>>>(gp);

  // K + V projections fused across blockIdx.y
  gp.A = key_;  gp.B = WkT; gp.bias = bk; gp.C = Kb;
  gp.A2 = value; gp.B2 = WvT; gp.bias2 = bv; gp.C2 = Vb;
  gp.N = 512; gp.ldb = 2048; gp.ldc = 512;
  gemm_kernel<true><<<dim3(128, 2), 256, 0, stream>>>(gp);
  gp.A2 = nullptr; gp.B2 = nullptr; gp.bias2 = nullptr; gp.C2 = nullptr;

  // V transpose per batch: VT[b][512][1024] = Vb[b][1024][512]^T
  transpose_cvt_kernel<false><<<dim3(16, 32, 4), tb, 0, stream>>>(
      Vb, VT, 1024, 512, 1024L * 512, 512L * 1024);

  // fused scores/softmax/PV
  fused_attn_kernel<<<dim3(32, 64), 512, 0, stream>>>(Qb, Kb, VT, attnF, AO);

  // O projection: AO [4096,2048] x WoT + bo -> outF fp32
  gp.A = AO; gp.B = WoT; gp.bias = bo; gp.C = outF;
  gp.M = 4096; gp.N = 2048; gp.K = 2048; gp.lda = 2048; gp.ldb = 2048; gp.ldc = 2048;
  gp.scale = 1.f; gp.out_bf16 = 0;
  gemm_kernel<false><<<dim3(512, 1), 256, 0, stream>>>(gp);
}

// Round 7
// 332.106 us; speedup vs baseline: 1.4294x; 1.0818x over previous
//
#include <hip/hip_runtime.h>

typedef unsigned short u16;
typedef __attribute__((ext_vector_type(8))) short short8;
typedef __attribute__((ext_vector_type(4))) float f32x4;

__device__ __forceinline__ u16 f2bf(float f) {
  union { float f; unsigned u; } a; a.f = f;
  unsigned u = a.u;
  u += 0x7fffu + ((u >> 16) & 1u);
  return (u16)(u >> 16);
}

// ---------------- transpose + convert: dst[c][r] = (bf16)src[r][c] ----------------
template<bool SRC_F32>
__global__ __launch_bounds__(256)
void transpose_cvt_kernel(const void* src_, u16* dst, int R, int C,
                          long sbatch, long dbatch) {
  const int bz = blockIdx.z;
  const float* sf = (const float*)src_ + (long)bz * sbatch;
  const u16*   sh = (const u16*)src_ + (long)bz * sbatch;
  dst += (long)bz * dbatch;
  __shared__ u16 tile[32][33];
  const int c0 = blockIdx.x * 32, r0 = blockIdx.y * 32;
  const int tx = threadIdx.x, ty = threadIdx.y;
#pragma unroll
  for (int i = 0; i < 4; ++i) {
    int r = r0 + ty + i * 8;
    u16 v;
    if (SRC_F32) v = f2bf(sf[(long)r * C + c0 + tx]);
    else         v = sh[(long)r * C + c0 + tx];
    tile[ty + i * 8][tx] = v;
  }
  __syncthreads();
#pragma unroll
  for (int i = 0; i < 4; ++i) {
    int rr = ty + i * 8;
    dst[(long)(c0 + rr) * R + r0 + tx] = tile[tx][rr];
  }
}

// ---------------- GEMM: C[m][n] = scale * sum_k A[m][k] * Bt[n][k] + bias[n] ------
#define BM 128
#define BN 128
#define BK 64

struct GemmParams {
  const void* A;
  const u16* B;
  const float* bias;
  void* C;
  const void* A2;
  const u16* B2;
  const float* bias2;
  void* C2;
  int M, N, K, lda, ldb, ldc;
  int div1, div2, out_bf16;
  long sA1, sA2, sB1, sB2, sC1, sC2;
  float scale;
};

template<bool AF32>
__global__ __launch_bounds__(256, 2)
void gemm_kernel(GemmParams p) {
  __shared__ __align__(16) u16 lds[2][2][BM * BK];
  const int t = threadIdx.x;
  const int w = t >> 6, l = t & 63;
  const int z = blockIdx.y;
  const int nTn = p.N / BN;
  const int tm = (blockIdx.x / nTn) * BM;
  const int tn = (blockIdx.x % nTn) * BN;

  const void* Asel = p.A; const u16* Bsel = p.B;
  void* Csel = p.C; const float* biasSel = p.bias;
  long offA = (long)(z / p.div1) * p.sA1 + (long)(z % p.div1) * p.sA2;
  long offB = (long)(z / p.div1) * p.sB1 + (long)((z % p.div1) / p.div2) * p.sB2;
  long offC = (long)(z / p.div1) * p.sC1 + (long)(z % p.div1) * p.sC2;
  if (p.A2) {
    offA = offB = offC = 0;
    if (z) { Asel = p.A2; Bsel = p.B2; Csel = p.C2; biasSel = p.bias2; }
  }

  const u16*   Ab = (const u16*)Asel + offA + (long)tm * p.lda;
  const float* Af = (const float*)Asel + offA + (long)tm * p.lda;
  const u16*   Bt = Bsel + offB + (long)tn * p.ldb;

  const int wr = w >> 1, wc = w & 1;
  f32x4 acc[4][4] = {};
  float aR[32];

  auto stageB = [&](int kt, int buf) {
#pragma unroll
    for (int i = 0; i < 4; ++i) {
      int c = i * 256 + t;
      int row = c >> 3;
      int slot = (c & 7) ^ (row & 7);
      const u16* gp = Bt + kt * BK + (long)row * p.ldb + slot * 8;
      u16* lp = &lds[buf][1][(i * 256 + w * 64) * 8];
      __builtin_amdgcn_global_load_lds(
          (const __attribute__((address_space(1))) unsigned int*)gp,
          (__attribute__((address_space(3))) unsigned int*)lp, 16, 0, 0);
    }
  };
  auto stageA_bf16 = [&](int kt, int buf) {
#pragma unroll
    for (int i = 0; i < 4; ++i) {
      int c = i * 256 + t;
      int row = c >> 3;
      int slot = (c & 7) ^ (row & 7);
      const u16* gp = Ab + kt * BK + (long)row * p.lda + slot * 8;
      u16* lp = &lds[buf][0][(i * 256 + w * 64) * 8];
      __builtin_amdgcn_global_load_lds(
          (const __attribute__((address_space(1))) unsigned int*)gp,
          (__attribute__((address_space(3))) unsigned int*)lp, 16, 0, 0);
    }
  };
  auto loadA_f32 = [&](int kt) {
    const float* g0 = Af + kt * BK;
#pragma unroll
    for (int i = 0; i < 4; ++i) {
      int c = i * 256 + t;
      int row = c >> 3, slot = c & 7;
      const float4* gp = (const float4*)(g0 + (long)row * p.lda + slot * 8);
      float4 v0 = gp[0], v1 = gp[1];
      aR[i * 8 + 0] = v0.x; aR[i * 8 + 1] = v0.y; aR[i * 8 + 2] = v0.z; aR[i * 8 + 3] = v0.w;
      aR[i * 8 + 4] = v1.x; aR[i * 8 + 5] = v1.y; aR[i * 8 + 6] = v1.z; aR[i * 8 + 7] = v1.w;
    }
  };
  auto writeA = [&](int buf) {
#pragma unroll
    for (int i = 0; i < 4; ++i) {
      int c = i * 256 + t;
      int row = c >> 3, slot = c & 7;
      short8 o;
#pragma unroll
      for (int j = 0; j < 8; ++j) o[j] = (short)f2bf(aR[i * 8 + j]);
      *(short8*)&lds[buf][0][row * 64 + ((slot ^ (row & 7)) * 8)] = o;
    }
  };
  auto compute = [&](int buf) {
    const u16* At  = lds[buf][0];
    const u16* Btl = lds[buf][1];
#pragma unroll
    for (int ks = 0; ks < 2; ++ks) {
      short8 af[4], bfr[4];
#pragma unroll
      for (int mi = 0; mi < 4; ++mi) {
        int row = wr * 64 + mi * 16 + (l & 15);
        int slot = (ks * 4 + (l >> 4)) ^ (row & 7);
        af[mi] = *(const short8*)&At[row * 64 + slot * 8];
      }
#pragma unroll
      for (int ni = 0; ni < 4; ++ni) {
        int row = wc * 64 + ni * 16 + (l & 15);
        int slot = (ks * 4 + (l >> 4)) ^ (row & 7);
        bfr[ni] = *(const short8*)&Btl[row * 64 + slot * 8];
      }
#pragma unroll
      for (int mi = 0; mi < 4; ++mi)
#pragma unroll
        for (int ni = 0; ni < 4; ++ni)
          acc[mi][ni] = __builtin_amdgcn_mfma_f32_16x16x32_bf16(
              af[mi], bfr[ni], acc[mi][ni], 0, 0, 0);
    }
  };

  const int nkt = p.K / BK;
  if (AF32) { loadA_f32(0); stageB(0, 0); writeA(0); }
  else      { stageA_bf16(0, 0); stageB(0, 0); }
  __syncthreads();

  int buf = 0;
  for (int kt = 0; kt < nkt; ++kt) {
    if (kt + 1 < nkt) {
      if (AF32) loadA_f32(kt + 1); else stageA_bf16(kt + 1, buf ^ 1);
      stageB(kt + 1, buf ^ 1);
    }
    compute(buf);
    if (AF32 && kt + 1 < nkt) writeA(buf ^ 1);
    __syncthreads();
    buf ^= 1;
  }

  const int cl = l & 15, rj = (l >> 4) * 4;
#pragma unroll
  for (int mi = 0; mi < 4; ++mi) {
#pragma unroll
    for (int ni = 0; ni < 4; ++ni) {
      int cidx = tn + wc * 64 + ni * 16 + cl;
      float bv = biasSel ? biasSel[cidx] : 0.f;
#pragma unroll
      for (int j = 0; j < 4; ++j) {
        int r = tm + wr * 64 + mi * 16 + rj + j;
        float v = acc[mi][ni][j] * p.scale + bv;
        long idx = offC + (long)r * p.ldc + cidx;
        if (p.out_bf16) ((u16*)Csel)[idx] = f2bf(v);
        else            ((float*)Csel)[idx] = v;
      }
    }
  }
}

// ---------------- fused scores -> softmax -> PV (swapped-MFMA, safe 2-phase) ------
// grid (32 qblocks, 64 b*h), 512 threads = 8 waves (wq 0..1, wcol 0..3).
// Scores use mfma(K, Q): lane holds S[k][q] with q = wq*16+(l&15) fixed per lane ->
// per-lane softmax, float4 attn stores, P packed in regs, 64-col P chunks via LDS.
// Sync: proven T3 minimum 2-phase only — STAGE(next, buf^1); compute(buf);
// __syncthreads() (full compiler-managed waitcnt). No raw barriers, no counted vmcnt.
__global__ __launch_bounds__(512, 4)
void fused_attn_kernel(const u16* __restrict__ Qg, const u16* __restrict__ Kg,
                       const u16* __restrict__ Vg, float* __restrict__ attnF,
                       u16* __restrict__ AO) {
  __shared__ __align__(16) u16 kv[2][64 * 128];   // 2 x 16 KB double buffer
  __shared__ __align__(16) u16 p2[2][32 * 64];    // 8 KB: Q stage first, then P chunks
  __shared__ float red[2][4][32];

  const int t = threadIdx.x;
  const int w = t >> 6, l = t & 63;
  const int wq = w >> 2, wcol = w & 3;
  const int qb = blockIdx.x, z = blockIdx.y;
  const int b = z >> 4, h = z & 15, g = h >> 2;
  const int q0 = qb * 32;
  const int qi = wq * 16 + (l & 15);       // this lane's q row (local)

  const u16* Qbase = Qg + ((long)b * 1024 + q0) * 2048 + h * 128;
  const u16* Kbase = Kg + (long)b * 1024 * 512 + g * 128;
  const u16* Vbase = Vg + ((long)b * 512 + g * 128) * 1024;  // VT: rows=d, cols=s
  float* attnO = attnF + ((long)z * 1024 + q0) * 1024;

  auto glds16 = [](const u16* gp, u16* lp) {
    __builtin_amdgcn_global_load_lds(
        (const __attribute__((address_space(1))) unsigned int*)gp,
        (__attribute__((address_space(3))) unsigned int*)lp, 16, 0, 0);
  };
  auto stageK = [&](int c, int buf) {      // [64 s][16 blocks of 8 d], src pre-swizzled
#pragma unroll
    for (int i = 0; i < 2; ++i) {
      int idx = i * 512 + t;
      int row = idx >> 4, blk = idx & 15;
      glds16(Kbase + (long)(c * 64 + row) * 512 + ((blk ^ (row & 7)) * 8),
             &kv[buf][(i * 512 + w * 64) * 8]);
    }
  };
  auto stageV = [&](int c, int buf) {      // [128 d][8 blocks of 8 s]
#pragma unroll
    for (int i = 0; i < 2; ++i) {
      int idx = i * 512 + t;
      int row = idx >> 3, blk = idx & 7;
      glds16(Vbase + (long)row * 1024 + c * 64 + ((blk ^ (row & 7)) * 8),
             &kv[buf][(i * 512 + w * 64) * 8]);
    }
  };

  // prologue: Q (1 load/thread) into p2, K0 into kv[0]
  {
    int row = t >> 4, blk = t & 15;
    glds16(Qbase + (long)row * 2048 + ((blk ^ (row & 7)) * 8), &((u16*)p2)[(w * 64) * 8]);
  }
  stageK(0, 0);
  __syncthreads();

  short8 qf[4];
  {
    const u16* pq = (const u16*)p2;
#pragma unroll
    for (int ks = 0; ks < 4; ++ks) {
      int slot = (ks * 4 + (l >> 4)) ^ (qi & 7);
      qf[ks] = *(const short8*)&pq[qi * 128 + slot * 8];
    }
  }

  f32x4 acc[16];
#pragma unroll
  for (int c = 0; c < 16; ++c) acc[c] = (f32x4){0.f, 0.f, 0.f, 0.f};

  // ---- scores: acc[c] = S[k = c*64 + wcol*16 + (l>>4)*4+j][q = qi]
  const int krow = wcol * 16 + (l & 15);
#pragma unroll
  for (int c = 0; c < 16; ++c) {
    if (c < 15) stageK(c + 1, (c + 1) & 1);
    else        stageV(0, 0);              // kv[0] free: last read at c=14
    const u16* Kl = kv[c & 1];
#pragma unroll
    for (int ks = 0; ks < 4; ++ks) {
      int slot = (ks * 4 + (l >> 4)) ^ (krow & 7);
      short8 kf = *(const short8*)&Kl[krow * 128 + slot * 8];
      acc[c] = __builtin_amdgcn_mfma_f32_16x16x32_bf16(kf, qf[ks], acc[c], 0, 0, 0);
    }
    __syncthreads();                       // drains stage(c+1); kv[(c+1)&1] ready
  }

  // ---- softmax: per-lane over 64 values, then 2 shfl + cross-wave LDS reduce
  const float scale = 0.08838834764831845f;  // 1/sqrt(128)
  float jm[4] = {-1e30f, -1e30f, -1e30f, -1e30f};
#pragma unroll
  for (int c = 0; c < 16; ++c) {
#pragma unroll
    for (int j = 0; j < 4; ++j) jm[j] = fmaxf(jm[j], acc[c][j]);
  }
  float mx = fmaxf(fmaxf(jm[0], jm[1]), fmaxf(jm[2], jm[3]));
  mx = fmaxf(mx, __shfl_xor(mx, 16));
  mx = fmaxf(mx, __shfl_xor(mx, 32));
  if ((l >> 4) == 0) red[0][wcol][qi] = mx;
  __syncthreads();
  const float m = fmaxf(fmaxf(red[0][0][qi], red[0][1][qi]),
                        fmaxf(red[0][2][qi], red[0][3][qi]));
  float s4[4] = {0.f, 0.f, 0.f, 0.f};
#pragma unroll
  for (int c = 0; c < 16; ++c) {
#pragma unroll
    for (int j = 0; j < 4; ++j) {
      float e = __expf((acc[c][j] - m) * scale);
      acc[c][j] = e;
      s4[j] += e;
    }
  }
  float ss = (s4[0] + s4[1]) + (s4[2] + s4[3]);
  ss += __shfl_xor(ss, 16);
  ss += __shfl_xor(ss, 32);
  if ((l >> 4) == 0) red[1][wcol][qi] = ss;
  __syncthreads();
  const float inv = 1.0f / (red[1][0][qi] + red[1][1][qi] + red[1][2][qi] + red[1][3][qi]);

  // ---- normalize: float4 attn stores + pack P to bf16 pairs in regs
  unsigned pk0[16], pk1[16];
#pragma unroll
  for (int c = 0; c < 16; ++c) {
    f32x4 v = acc[c] * inv;
    *(f32x4*)(attnO + (long)qi * 1024 + c * 64 + wcol * 16 + ((l >> 4) * 4)) = v;
    pk0[c] = (unsigned)f2bf(v[0]) | ((unsigned)f2bf(v[1]) << 16);
    pk1[c] = (unsigned)f2bf(v[2]) | ((unsigned)f2bf(v[3]) << 16);
  }

  // ---- PV with P chunks through p2 (double-buffered) + V double buffer
  const int kloc = wcol * 16 + ((l >> 4) * 4);       // k-position within chunk
  auto pwrite = [&](int pb, unsigned v0, unsigned v1) {
    int blk = (kloc >> 3) ^ (qi & 7);
    uint2 val; val.x = v0; val.y = v1;
    *(uint2*)&p2[pb][qi * 64 + blk * 8 + (kloc & 7)] = val;
  };

  pwrite(0, pk0[0], pk1[0]);     // P0 -> p2[0] (Q dead)
  __syncthreads();               // P0 visible; V0 (staged at c=15) drained

  f32x4 acc2[2] = {};
  const int prow = wq * 16 + (l & 15);
#pragma unroll
  for (int c2 = 0; c2 < 16; ++c2) {
    if (c2 < 15) {
      stageV(c2 + 1, (c2 + 1) & 1);                  // kv[(c2+1)&1] free since c2-1
      pwrite((c2 + 1) & 1, pk0[c2 + 1], pk1[c2 + 1]); // p2[(c2+1)&1] free since c2-1
    }
    const u16* Vl = kv[c2 & 1];
#pragma unroll
    for (int ks = 0; ks < 2; ++ks) {
      int ablk = (ks * 4 + (l >> 4)) ^ (prow & 7);
      short8 af = *(const short8*)&p2[c2 & 1][prow * 64 + ablk * 8];
#pragma unroll
      for (int ni = 0; ni < 2; ++ni) {
        int vrow = wcol * 32 + ni * 16 + (l & 15);
        int vslot = (ks * 4 + (l >> 4)) ^ (vrow & 7);
        short8 vf = *(const short8*)&Vl[vrow * 64 + vslot * 8];
        acc2[ni] = __builtin_amdgcn_mfma_f32_16x16x32_bf16(af, vf, acc2[ni], 0, 0, 0);
      }
    }
    __syncthreads();             // drains stageV(c2+1) + pwrite; next buffers ready
  }

  // ---- write AO (bf16): q = wq*16 + (l>>4)*4 + j, d = wcol*32 + ni*16 + (l&15)
  u16* AObase = AO + ((long)b * 1024 + q0) * 2048 + h * 128;
#pragma unroll
  for (int ni = 0; ni < 2; ++ni)
#pragma unroll
    for (int j = 0; j < 4; ++j) {
      int qq = wq * 16 + (l >> 4) * 4 + j;
      int d = wcol * 32 + ni * 16 + (l & 15);
      AObase[(long)qq * 2048 + d] = f2bf(acc2[ni][j]);
    }
}

// ---------------- host ----------------
extern "C" void kernel_launch(void* const* d_in, const int* in_sizes, int n_in,
                              void* d_out, int out_size, void* d_ws, size_t ws_size,
                              hipStream_t stream) {
  const float* query = (const float*)d_in[0];
  const float* key_  = (const float*)d_in[1];
  const float* value = (const float*)d_in[2];
  const float* Wq = (const float*)d_in[3]; const float* bq = (const float*)d_in[4];
  const float* Wk = (const float*)d_in[5]; const float* bk = (const float*)d_in[6];
  const float* Wv = (const float*)d_in[7]; const float* bv = (const float*)d_in[8];
  const float* Wo = (const float*)d_in[9]; const float* bo = (const float*)d_in[10];

  float* outF  = (float*)d_out;                 // [4,1024,2048]
  float* attnF = outF + 8388608;                // [4,16,1024,1024]

  char* wp = (char*)d_ws;
  u16* WqT = (u16*)wp; wp += 2048L * 2048 * 2;
  u16* WkT = (u16*)wp; wp += 512L * 2048 * 2;
  u16* WvT = (u16*)wp; wp += 512L * 2048 * 2;
  u16* WoT = (u16*)wp; wp += 2048L * 2048 * 2;
  u16* Qb  = (u16*)wp; wp += 4096L * 2048 * 2;
  u16* Kb  = (u16*)wp; wp += 4096L * 512 * 2;
  u16* Vb  = (u16*)wp; wp += 4096L * 512 * 2;
  u16* VT  = (u16*)wp; wp += 4L * 512 * 1024 * 2;
  u16* AO  = (u16*)wp; wp += 4096L * 2048 * 2;

  dim3 tb(32, 8);
  transpose_cvt_kernel<true><<<dim3(64, 64, 1), tb, 0, stream>>>(Wq, WqT, 2048, 2048, 0, 0);
  transpose_cvt_kernel<true><<<dim3(16, 64, 1), tb, 0, stream>>>(Wk, WkT, 2048, 512, 0, 0);
  transpose_cvt_kernel<true><<<dim3(16, 64, 1), tb, 0, stream>>>(Wv, WvT, 2048, 512, 0, 0);
  transpose_cvt_kernel<true><<<dim3(64, 64, 1), tb, 0, stream>>>(Wo, WoT, 2048, 2048, 0, 0);

  GemmParams gp = {};
  gp.div1 = 1; gp.div2 = 1;
  gp.sA1 = gp.sA2 = gp.sB1 = gp.sB2 = gp.sC1 = gp.sC2 = 0;
  gp.scale = 1.f;

  // Q projection: [4096,2048] x WqT -> Qb bf16
  gp.A = query; gp.B = WqT; gp.bias = bq; gp.C = Qb;
  gp.M = 4096; gp.N = 2048; gp.K = 2048; gp.lda = 2048; gp.ldb = 2048; gp.ldc = 2048;
  gp.out_bf16 = 1;
  gemm_kernel<true><<<dim3(512, 1), 256, 0, stream>>>(gp);

  // K + V projections fused across blockIdx.y
  gp.A = key_;  gp.B = WkT; gp.bias = bk; gp.C = Kb;
  gp.A2 = value; gp.B2 = WvT; gp.bias2 = bv; gp.C2 = Vb;
  gp.N = 512; gp.ldb = 2048; gp.ldc = 512;
  gemm_kernel<true><<<dim3(128, 2), 256, 0, stream>>>(gp);
  gp.A2 = nullptr; gp.B2 = nullptr; gp.bias2 = nullptr; gp.C2 = nullptr;

  // V transpose per batch: VT[b][512][1024] = Vb[b][1024][512]^T
  transpose_cvt_kernel<false><<<dim3(16, 32, 4), tb, 0, stream>>>(
      Vb, VT, 1024, 512, 1024L * 512, 512L * 1024);

  // fused scores/softmax/PV
  fused_attn_kernel<<<dim3(32, 64), 512, 0, stream>>>(Qb, Kb, VT, attnF, AO);

  // O projection: AO [4096,2048] x WoT + bo -> outF fp32
  gp.A = AO; gp.B = WoT; gp.bias = bo; gp.C = outF;
  gp.M = 4096; gp.N = 2048; gp.K = 2048; gp.lda = 2048; gp.ldb = 2048; gp.ldc = 2048;
  gp.scale = 1.f; gp.out_bf16 = 0;
  gemm_kernel<false><<<dim3(512, 1), 256, 0, stream>>>(gp);
}

// Round 8
// 327.363 us; speedup vs baseline: 1.4501x; 1.0145x over previous
//
#include <hip/hip_runtime.h>

typedef unsigned short u16;
typedef __attribute__((ext_vector_type(8))) short short8;
typedef __attribute__((ext_vector_type(4))) float f32x4;

__device__ __forceinline__ u16 f2bf(float f) {
  union { float f; unsigned u; } a; a.f = f;
  unsigned u = a.u;
  u += 0x7fffu + ((u >> 16) & 1u);
  return (u16)(u >> 16);
}

// ---------------- merged weight transpose+cvt: dst[c][r] = (bf16)W[r][c] ----------
struct TP4 {
  const float *s0, *s1, *s2, *s3;
  u16 *d0, *d1, *d2, *d3;
};
__global__ __launch_bounds__(256)
void transpose4_kernel(TP4 tp) {
  const int z = blockIdx.z;
  const float* sf; u16* dst; int C;
  if      (z == 0) { sf = tp.s0; dst = tp.d0; C = 2048; }
  else if (z == 1) { sf = tp.s1; dst = tp.d1; C = 512;  }
  else if (z == 2) { sf = tp.s2; dst = tp.d2; C = 512;  }
  else             { sf = tp.s3; dst = tp.d3; C = 2048; }
  const int c0 = blockIdx.x * 32, r0 = blockIdx.y * 32;
  if (c0 >= C) return;
  const int R = 2048;
  __shared__ u16 tile[32][33];
  const int tx = threadIdx.x, ty = threadIdx.y;
#pragma unroll
  for (int i = 0; i < 4; ++i) {
    int r = r0 + ty + i * 8;
    tile[ty + i * 8][tx] = f2bf(sf[(long)r * C + c0 + tx]);
  }
  __syncthreads();
#pragma unroll
  for (int i = 0; i < 4; ++i) {
    int rr = ty + i * 8;
    dst[(long)(c0 + rr) * R + r0 + tx] = tile[tx][rr];
  }
}

// ---------------- GEMM: C[m][n] = scale * sum_k A[m][k] * Bt[n][k] + bias[n] ------
// out_mode: 0 = f32, 1 = bf16, 2 = bf16 transposed-batched (VT[b][n][s], b=r>>10)
#define BM 128
#define BN 128
#define BK 64

struct GemmParams {
  const void* A;
  const u16* B;
  const float* bias;
  void* C;
  const void* A2;
  const u16* B2;
  const float* bias2;
  void* C2;
  int M, N, K, lda, ldb, ldc;
  int div1, div2, out_mode, out_mode2;
  long sA1, sA2, sB1, sB2, sC1, sC2;
  float scale;
};

template<bool AF32>
__global__ __launch_bounds__(256, 2)
void gemm_kernel(GemmParams p) {
  __shared__ __align__(16) u16 lds[2][2][BM * BK];
  const int t = threadIdx.x;
  const int w = t >> 6, l = t & 63;
  const int z = blockIdx.y;
  const int nTn = p.N / BN;
  const int tm = (blockIdx.x / nTn) * BM;
  const int tn = (blockIdx.x % nTn) * BN;

  const void* Asel = p.A; const u16* Bsel = p.B;
  void* Csel = p.C; const float* biasSel = p.bias;
  int mode = p.out_mode;
  long offA = (long)(z / p.div1) * p.sA1 + (long)(z % p.div1) * p.sA2;
  long offB = (long)(z / p.div1) * p.sB1 + (long)((z % p.div1) / p.div2) * p.sB2;
  long offC = (long)(z / p.div1) * p.sC1 + (long)(z % p.div1) * p.sC2;
  if (p.A2) {
    offA = offB = offC = 0;
    if (z) { Asel = p.A2; Bsel = p.B2; Csel = p.C2; biasSel = p.bias2; mode = p.out_mode2; }
  }

  const u16*   Ab = (const u16*)Asel + offA + (long)tm * p.lda;
  const float* Af = (const float*)Asel + offA + (long)tm * p.lda;
  const u16*   Bt = Bsel + offB + (long)tn * p.ldb;

  const int wr = w >> 1, wc = w & 1;
  f32x4 acc[4][4] = {};
  float aR[32];

  auto stageB = [&](int kt, int buf) {
#pragma unroll
    for (int i = 0; i < 4; ++i) {
      int c = i * 256 + t;
      int row = c >> 3;
      int slot = (c & 7) ^ (row & 7);
      const u16* gp = Bt + kt * BK + (long)row * p.ldb + slot * 8;
      u16* lp = &lds[buf][1][(i * 256 + w * 64) * 8];
      __builtin_amdgcn_global_load_lds(
          (const __attribute__((address_space(1))) unsigned int*)gp,
          (__attribute__((address_space(3))) unsigned int*)lp, 16, 0, 0);
    }
  };
  auto stageA_bf16 = [&](int kt, int buf) {
#pragma unroll
    for (int i = 0; i < 4; ++i) {
      int c = i * 256 + t;
      int row = c >> 3;
      int slot = (c & 7) ^ (row & 7);
      const u16* gp = Ab + kt * BK + (long)row * p.lda + slot * 8;
      u16* lp = &lds[buf][0][(i * 256 + w * 64) * 8];
      __builtin_amdgcn_global_load_lds(
          (const __attribute__((address_space(1))) unsigned int*)gp,
          (__attribute__((address_space(3))) unsigned int*)lp, 16, 0, 0);
    }
  };
  auto loadA_f32 = [&](int kt) {
    const float* g0 = Af + kt * BK;
#pragma unroll
    for (int i = 0; i < 4; ++i) {
      int c = i * 256 + t;
      int row = c >> 3, slot = c & 7;
      const float4* gp = (const float4*)(g0 + (long)row * p.lda + slot * 8);
      float4 v0 = gp[0], v1 = gp[1];
      aR[i * 8 + 0] = v0.x; aR[i * 8 + 1] = v0.y; aR[i * 8 + 2] = v0.z; aR[i * 8 + 3] = v0.w;
      aR[i * 8 + 4] = v1.x; aR[i * 8 + 5] = v1.y; aR[i * 8 + 6] = v1.z; aR[i * 8 + 7] = v1.w;
    }
  };
  auto writeA = [&](int buf) {
#pragma unroll
    for (int i = 0; i < 4; ++i) {
      int c = i * 256 + t;
      int row = c >> 3, slot = c & 7;
      short8 o;
#pragma unroll
      for (int j = 0; j < 8; ++j) o[j] = (short)f2bf(aR[i * 8 + j]);
      *(short8*)&lds[buf][0][row * 64 + ((slot ^ (row & 7)) * 8)] = o;
    }
  };
  auto compute = [&](int buf) {
    const u16* At  = lds[buf][0];
    const u16* Btl = lds[buf][1];
#pragma unroll
    for (int ks = 0; ks < 2; ++ks) {
      short8 af[4], bfr[4];
#pragma unroll
      for (int mi = 0; mi < 4; ++mi) {
        int row = wr * 64 + mi * 16 + (l & 15);
        int slot = (ks * 4 + (l >> 4)) ^ (row & 7);
        af[mi] = *(const short8*)&At[row * 64 + slot * 8];
      }
#pragma unroll
      for (int ni = 0; ni < 4; ++ni) {
        int row = wc * 64 + ni * 16 + (l & 15);
        int slot = (ks * 4 + (l >> 4)) ^ (row & 7);
        bfr[ni] = *(const short8*)&Btl[row * 64 + slot * 8];
      }
#pragma unroll
      for (int mi = 0; mi < 4; ++mi)
#pragma unroll
        for (int ni = 0; ni < 4; ++ni)
          acc[mi][ni] = __builtin_amdgcn_mfma_f32_16x16x32_bf16(
              af[mi], bfr[ni], acc[mi][ni], 0, 0, 0);
    }
  };

  const int nkt = p.K / BK;
  if (AF32) { loadA_f32(0); stageB(0, 0); writeA(0); }
  else      { stageA_bf16(0, 0); stageB(0, 0); }
  __syncthreads();

  int buf = 0;
  for (int kt = 0; kt < nkt; ++kt) {
    if (kt + 1 < nkt) {
      if (AF32) loadA_f32(kt + 1); else stageA_bf16(kt + 1, buf ^ 1);
      stageB(kt + 1, buf ^ 1);
    }
    compute(buf);
    if (AF32 && kt + 1 < nkt) writeA(buf ^ 1);
    __syncthreads();
    buf ^= 1;
  }

  const int cl = l & 15, rj = (l >> 4) * 4;
#pragma unroll
  for (int mi = 0; mi < 4; ++mi) {
#pragma unroll
    for (int ni = 0; ni < 4; ++ni) {
      int cidx = tn + wc * 64 + ni * 16 + cl;
      float bv = biasSel ? biasSel[cidx] : 0.f;
#pragma unroll
      for (int j = 0; j < 4; ++j) {
        int r = tm + wr * 64 + mi * 16 + rj + j;
        float v = acc[mi][ni][j] * p.scale + bv;
        if (mode == 2) {
          // VT[b][cidx][s]: b = r>>10, s = r&1023 (ld 1024, batch stride 512*1024)
          ((u16*)Csel)[((long)(r >> 10)) * 524288 + (long)cidx * 1024 + (r & 1023)] = f2bf(v);
        } else {
          long idx = offC + (long)r * p.ldc + cidx;
          if (mode == 1) ((u16*)Csel)[idx] = f2bf(v);
          else           ((float*)Csel)[idx] = v;
        }
      }
    }
  }
}

// ---------------- fused scores -> softmax -> PV (swapped-MFMA, safe 2-phase) ------
// grid (32 qblocks, 64 b*h), 512 threads = 8 waves (wq 0..1, wcol 0..3).
// Scores: K-chunks staged in PAIRS (8 phases x 8 MFMA). PV: 16 phases, V staged
// at distance 2. Sync: only {STAGE(next); compute(cur); __syncthreads()}.
__global__ __launch_bounds__(512, 4)
void fused_attn_kernel(const u16* __restrict__ Qg, const u16* __restrict__ Kg,
                       const u16* __restrict__ Vg, float* __restrict__ attnF,
                       u16* __restrict__ AO) {
  __shared__ __align__(16) u16 kv[2][2][64 * 128];  // 64 KB (pair buffers x 2 subs)
  __shared__ __align__(16) u16 p2[2][32 * 64];      // 8 KB: Q stage first, then P chunks
  __shared__ float red[2][4][32];                   // 1 KB

  const int t = threadIdx.x;
  const int w = t >> 6, l = t & 63;
  const int wq = w >> 2, wcol = w & 3;
  const int qb = blockIdx.x, z = blockIdx.y;
  const int b = z >> 4, h = z & 15, g = h >> 2;
  const int q0 = qb * 32;
  const int qi = wq * 16 + (l & 15);       // this lane's q row (local)

  const u16* Qbase = Qg + ((long)b * 1024 + q0) * 2048 + h * 128;
  const u16* Kbase = Kg + (long)b * 1024 * 512 + g * 128;
  const u16* Vbase = Vg + ((long)b * 512 + g * 128) * 1024;  // VT: rows=d, cols=s
  float* attnO = attnF + ((long)z * 1024 + q0) * 1024;

  auto glds16 = [](const u16* gp, u16* lp) {
    __builtin_amdgcn_global_load_lds(
        (const __attribute__((address_space(1))) unsigned int*)gp,
        (__attribute__((address_space(3))) unsigned int*)lp, 16, 0, 0);
  };
  auto stageK = [&](int c, int pb, int sub) {  // [64 s][16 blocks of 8 d]
#pragma unroll
    for (int i = 0; i < 2; ++i) {
      int idx = i * 512 + t;
      int row = idx >> 4, blk = idx & 15;
      glds16(Kbase + (long)(c * 64 + row) * 512 + ((blk ^ (row & 7)) * 8),
             &kv[pb][sub][(i * 512 + w * 64) * 8]);
    }
  };
  auto stageV = [&](int c, int pb, int sub) {  // [128 d][8 blocks of 8 s]
#pragma unroll
    for (int i = 0; i < 2; ++i) {
      int idx = i * 512 + t;
      int row = idx >> 3, blk = idx & 7;
      glds16(Vbase + (long)row * 1024 + c * 64 + ((blk ^ (row & 7)) * 8),
             &kv[pb][sub][(i * 512 + w * 64) * 8]);
    }
  };

  // prologue: Q (1 load/thread) into p2 (spans both buffers), K0+K1 into kv[0]
  {
    int row = t >> 4, blk = t & 15;
    glds16(Qbase + (long)row * 2048 + ((blk ^ (row & 7)) * 8), &((u16*)p2)[(w * 64) * 8]);
  }
  stageK(0, 0, 0);
  stageK(1, 0, 1);
  __syncthreads();

  short8 qf[4];
  {
    const u16* pq = (const u16*)p2;
#pragma unroll
    for (int ks = 0; ks < 4; ++ks) {
      int slot = (ks * 4 + (l >> 4)) ^ (qi & 7);
      qf[ks] = *(const short8*)&pq[qi * 128 + slot * 8];
    }
  }

  f32x4 acc[16];
#pragma unroll
  for (int c = 0; c < 16; ++c) acc[c] = (f32x4){0.f, 0.f, 0.f, 0.f};

  // ---- scores: 8 pair-phases; acc[c] = S[k = c*64 + wcol*16 + (l>>4)*4+j][q = qi]
  const int krow = wcol * 16 + (l & 15);
#pragma unroll
  for (int pph = 0; pph < 8; ++pph) {
    if (pph < 7) {
      stageK(2 * pph + 2, (pph + 1) & 1, 0);
      stageK(2 * pph + 3, (pph + 1) & 1, 1);
    } else {
      stageV(0, 0, 0);   // kv[0] free since pair-phase 6
      stageV(1, 0, 1);
    }
    __builtin_amdgcn_s_setprio(1);
#pragma unroll
    for (int sub = 0; sub < 2; ++sub) {
      const int c = 2 * pph + sub;
      const u16* Kl = kv[pph & 1][sub];
#pragma unroll
      for (int ks = 0; ks < 4; ++ks) {
        int slot = (ks * 4 + (l >> 4)) ^ (krow & 7);
        short8 kf = *(const short8*)&Kl[krow * 128 + slot * 8];
        acc[c] = __builtin_amdgcn_mfma_f32_16x16x32_bf16(kf, qf[ks], acc[c], 0, 0, 0);
      }
    }
    __builtin_amdgcn_s_setprio(0);
    __syncthreads();                       // drains stages; next pair ready
  }

  // ---- softmax: per-lane over 64 values, then 2 shfl + cross-wave LDS reduce
  const float scale = 0.08838834764831845f;  // 1/sqrt(128)
  float jm[4] = {-1e30f, -1e30f, -1e30f, -1e30f};
#pragma unroll
  for (int c = 0; c < 16; ++c) {
#pragma unroll
    for (int j = 0; j < 4; ++j) jm[j] = fmaxf(jm[j], acc[c][j]);
  }
  float mx = fmaxf(fmaxf(jm[0], jm[1]), fmaxf(jm[2], jm[3]));
  mx = fmaxf(mx, __shfl_xor(mx, 16));
  mx = fmaxf(mx, __shfl_xor(mx, 32));
  if ((l >> 4) == 0) red[0][wcol][qi] = mx;
  __syncthreads();
  const float m = fmaxf(fmaxf(red[0][0][qi], red[0][1][qi]),
                        fmaxf(red[0][2][qi], red[0][3][qi]));
  float s4[4] = {0.f, 0.f, 0.f, 0.f};
#pragma unroll
  for (int c = 0; c < 16; ++c) {
#pragma unroll
    for (int j = 0; j < 4; ++j) {
      float e = __expf((acc[c][j] - m) * scale);
      acc[c][j] = e;
      s4[j] += e;
    }
  }
  float ss = (s4[0] + s4[1]) + (s4[2] + s4[3]);
  ss += __shfl_xor(ss, 16);
  ss += __shfl_xor(ss, 32);
  if ((l >> 4) == 0) red[1][wcol][qi] = ss;
  __syncthreads();
  const float inv = 1.0f / (red[1][0][qi] + red[1][1][qi] + red[1][2][qi] + red[1][3][qi]);

  // ---- normalize in place + float4 attn stores (acc[] now holds P)
#pragma unroll
  for (int c = 0; c < 16; ++c) {
    acc[c] = acc[c] * inv;
    *(f32x4*)(attnO + (long)qi * 1024 + c * 64 + wcol * 16 + ((l >> 4) * 4)) = acc[c];
  }

  // ---- PV: P chunks packed from acc at write time (no pk register arrays)
  const int kloc = wcol * 16 + ((l >> 4) * 4);       // k-position within chunk
  auto pwrite = [&](int pb, const f32x4& a) {
    int blk = (kloc >> 3) ^ (qi & 7);
    uint2 val;
    val.x = (unsigned)f2bf(a[0]) | ((unsigned)f2bf(a[1]) << 16);
    val.y = (unsigned)f2bf(a[2]) | ((unsigned)f2bf(a[3]) << 16);
    *(uint2*)&p2[pb][qi * 64 + blk * 8 + (kloc & 7)] = val;
  };

  pwrite(0, acc[0]);             // P0 -> p2[0] (Q dead)
  __syncthreads();               // P0 visible; V0/V1 (staged at pph=7) drained

  f32x4 acc2[2] = {};
  const int prow = wq * 16 + (l & 15);
#pragma unroll
  for (int c2 = 0; c2 < 16; ++c2) {
    if (c2 < 15) pwrite((c2 + 1) & 1, acc[c2 + 1]);
    if (c2 < 14) stageV(c2 + 2, ((c2 + 2) >> 1) & 1, (c2 + 2) & 1);  // distance-2 prefetch
    const u16* Vl = kv[(c2 >> 1) & 1][c2 & 1];
    __builtin_amdgcn_s_setprio(1);
#pragma unroll
    for (int ks = 0; ks < 2; ++ks) {
      int ablk = (ks * 4 + (l >> 4)) ^ (prow & 7);
      short8 af = *(const short8*)&p2[c2 & 1][prow * 64 + ablk * 8];
#pragma unroll
      for (int ni = 0; ni < 2; ++ni) {
        int vrow = wcol * 32 + ni * 16 + (l & 15);
        int vslot = (ks * 4 + (l >> 4)) ^ (vrow & 7);
        short8 vf = *(const short8*)&Vl[vrow * 64 + vslot * 8];
        acc2[ni] = __builtin_amdgcn_mfma_f32_16x16x32_bf16(af, vf, acc2[ni], 0, 0, 0);
      }
    }
    __builtin_amdgcn_s_setprio(0);
    __syncthreads();             // drains stageV + pwrite; next buffers ready
  }

  // ---- write AO (bf16): q = wq*16 + (l>>4)*4 + j, d = wcol*32 + ni*16 + (l&15)
  u16* AObase = AO + ((long)b * 1024 + q0) * 2048 + h * 128;
#pragma unroll
  for (int ni = 0; ni < 2; ++ni)
#pragma unroll
    for (int j = 0; j < 4; ++j) {
      int qq = wq * 16 + (l >> 4) * 4 + j;
      int d = wcol * 32 + ni * 16 + (l & 15);
      AObase[(long)qq * 2048 + d] = f2bf(acc2[ni][j]);
    }
}

// ---------------- host ----------------
extern "C" void kernel_launch(void* const* d_in, const int* in_sizes, int n_in,
                              void* d_out, int out_size, void* d_ws, size_t ws_size,
                              hipStream_t stream) {
  const float* query = (const float*)d_in[0];
  const float* key_  = (const float*)d_in[1];
  const float* value = (const float*)d_in[2];
  const float* Wq = (const float*)d_in[3]; const float* bq = (const float*)d_in[4];
  const float* Wk = (const float*)d_in[5]; const float* bk = (const float*)d_in[6];
  const float* Wv = (const float*)d_in[7]; const float* bv = (const float*)d_in[8];
  const float* Wo = (const float*)d_in[9]; const float* bo = (const float*)d_in[10];

  float* outF  = (float*)d_out;                 // [4,1024,2048]
  float* attnF = outF + 8388608;                // [4,16,1024,1024]

  char* wp = (char*)d_ws;
  u16* WqT = (u16*)wp; wp += 2048L * 2048 * 2;
  u16* WkT = (u16*)wp; wp += 512L * 2048 * 2;
  u16* WvT = (u16*)wp; wp += 512L * 2048 * 2;
  u16* WoT = (u16*)wp; wp += 2048L * 2048 * 2;
  u16* Qb  = (u16*)wp; wp += 4096L * 2048 * 2;
  u16* Kb  = (u16*)wp; wp += 4096L * 512 * 2;
  u16* VT  = (u16*)wp; wp += 4L * 512 * 1024 * 2;
  u16* AO  = (u16*)wp; wp += 4096L * 2048 * 2;

  // merged weight transposes (Wq, Wk, Wv, Wo)
  TP4 tp;
  tp.s0 = Wq; tp.s1 = Wk; tp.s2 = Wv; tp.s3 = Wo;
  tp.d0 = WqT; tp.d1 = WkT; tp.d2 = WvT; tp.d3 = WoT;
  transpose4_kernel<<<dim3(64, 64, 4), dim3(32, 8), 0, stream>>>(tp);

  GemmParams gp = {};
  gp.div1 = 1; gp.div2 = 1;
  gp.sA1 = gp.sA2 = gp.sB1 = gp.sB2 = gp.sC1 = gp.sC2 = 0;
  gp.scale = 1.f;

  // Q projection: [4096,2048] x WqT -> Qb bf16
  gp.A = query; gp.B = WqT; gp.bias = bq; gp.C = Qb;
  gp.M = 4096; gp.N = 2048; gp.K = 2048; gp.lda = 2048; gp.ldb = 2048; gp.ldc = 2048;
  gp.out_mode = 1;
  gemm_kernel<true><<<dim3(512, 1), 256, 0, stream>>>(gp);

  // K + V projections fused across blockIdx.y; V writes VT (transposed) directly
  gp.A = key_;  gp.B = WkT; gp.bias = bk; gp.C = Kb;  gp.out_mode = 1;
  gp.A2 = value; gp.B2 = WvT; gp.bias2 = bv; gp.C2 = VT; gp.out_mode2 = 2;
  gp.N = 512; gp.ldb = 2048; gp.ldc = 512;
  gemm_kernel<true><<<dim3(128, 2), 256, 0, stream>>>(gp);
  gp.A2 = nullptr; gp.B2 = nullptr; gp.bias2 = nullptr; gp.C2 = nullptr;

  // fused scores/softmax/PV
  fused_attn_kernel<<<dim3(32, 64), 512, 0, stream>>>(Qb, Kb, VT, attnF, AO);

  // O projection: AO [4096,2048] x WoT + bo -> outF fp32
  gp.A = AO; gp.B = WoT; gp.bias = bo; gp.C = outF;
  gp.M = 4096; gp.N = 2048; gp.K = 2048; gp.lda = 2048; gp.ldb = 2048; gp.ldc = 2048;
  gp.scale = 1.f; gp.out_mode = 0;
  gemm_kernel<false><<<dim3(512, 1), 256, 0, stream>>>(gp);
}

// Round 9
// 299.177 us; speedup vs baseline: 1.5867x; 1.0942x over previous
//
#include <hip/hip_runtime.h>

typedef unsigned short u16;
typedef __attribute__((ext_vector_type(8))) short short8;
typedef __attribute__((ext_vector_type(4))) float f32x4;

__device__ __forceinline__ u16 f2bf(float f) {
  union { float f; unsigned u; } a; a.f = f;
  unsigned u = a.u;
  u += 0x7fffu + ((u >> 16) & 1u);
  return (u16)(u >> 16);
}

// ---------------- merged weight transpose+cvt: dst[c][r] = (bf16)W[r][c] ----------
struct TP4 {
  const float *s0, *s1, *s2, *s3;
  u16 *d0, *d1, *d2, *d3;
};
__global__ __launch_bounds__(256)
void transpose4_kernel(TP4 tp) {
  const int z = blockIdx.z;
  const float* sf; u16* dst; int C;
  if      (z == 0) { sf = tp.s0; dst = tp.d0; C = 2048; }
  else if (z == 1) { sf = tp.s1; dst = tp.d1; C = 512;  }
  else if (z == 2) { sf = tp.s2; dst = tp.d2; C = 512;  }
  else             { sf = tp.s3; dst = tp.d3; C = 2048; }
  const int c0 = blockIdx.x * 32, r0 = blockIdx.y * 32;
  if (c0 >= C) return;
  const int R = 2048;
  __shared__ u16 tile[32][33];
  const int tx = threadIdx.x, ty = threadIdx.y;
#pragma unroll
  for (int i = 0; i < 4; ++i) {
    int r = r0 + ty + i * 8;
    tile[ty + i * 8][tx] = f2bf(sf[(long)r * C + c0 + tx]);
  }
  __syncthreads();
#pragma unroll
  for (int i = 0; i < 4; ++i) {
    int rr = ty + i * 8;
    dst[(long)(c0 + rr) * R + r0 + tx] = tile[tx][rr];
  }
}

// ---------------- GEMM (up to 3 independent problems per dispatch) ----------------
// C[m][n] = scale * sum_k A[m][k] * Bt[n][k] + bias[n]
// mode: 0 = f32 store, 1 = bf16 store, 2 = bf16 transposed-batched (VT[b][n][s])
#define BM 128
#define BN 128
#define BK 64

struct GemmP {
  const void* A;
  const u16* B;
  const float* bias;
  void* C;
  int N, K, lda, ldb, ldc, mode;
  float scale;
};
struct Gemm3 {
  GemmP q[3];
  int nb0, nb1;   // block counts of problems 0 and 1
  int nwg;        // total blocks (divisible by 8)
};

template<bool AF32>
__global__ __launch_bounds__(256, 2)
void gemm3_kernel(Gemm3 g) {
  __shared__ __align__(16) u16 lds[2][2][BM * BK];
  const int t = threadIdx.x;
  const int w = t >> 6, l = t & 63;

  // bijective XCD swizzle (nwg % 8 == 0)
  const int cpx = g.nwg >> 3;
  const int swz = (blockIdx.x & 7) * cpx + (blockIdx.x >> 3);
  int pi, local;
  if (swz < g.nb0)            { pi = 0; local = swz; }
  else if (swz < g.nb0 + g.nb1) { pi = 1; local = swz - g.nb0; }
  else                        { pi = 2; local = swz - g.nb0 - g.nb1; }
  const GemmP p = g.q[pi];

  const int nTn = p.N / BN;
  const int tm = (local / nTn) * BM;
  const int tn = (local % nTn) * BN;

  const u16*   Ab = (const u16*)p.A + (long)tm * p.lda;
  const float* Af = (const float*)p.A + (long)tm * p.lda;
  const u16*   Bt = p.B + (long)tn * p.ldb;

  const int wr = w >> 1, wc = w & 1;
  f32x4 acc[4][4] = {};
  float aR[32];

  auto stageB = [&](int kt, int buf) {
#pragma unroll
    for (int i = 0; i < 4; ++i) {
      int c = i * 256 + t;
      int row = c >> 3;
      int slot = (c & 7) ^ (row & 7);
      const u16* gp = Bt + kt * BK + (long)row * p.ldb + slot * 8;
      u16* lp = &lds[buf][1][(i * 256 + w * 64) * 8];
      __builtin_amdgcn_global_load_lds(
          (const __attribute__((address_space(1))) unsigned int*)gp,
          (__attribute__((address_space(3))) unsigned int*)lp, 16, 0, 0);
    }
  };
  auto stageA_bf16 = [&](int kt, int buf) {
#pragma unroll
    for (int i = 0; i < 4; ++i) {
      int c = i * 256 + t;
      int row = c >> 3;
      int slot = (c & 7) ^ (row & 7);
      const u16* gp = Ab + kt * BK + (long)row * p.lda + slot * 8;
      u16* lp = &lds[buf][0][(i * 256 + w * 64) * 8];
      __builtin_amdgcn_global_load_lds(
          (const __attribute__((address_space(1))) unsigned int*)gp,
          (__attribute__((address_space(3))) unsigned int*)lp, 16, 0, 0);
    }
  };
  auto loadA_f32 = [&](int kt) {
    const float* g0 = Af + kt * BK;
#pragma unroll
    for (int i = 0; i < 4; ++i) {
      int c = i * 256 + t;
      int row = c >> 3, slot = c & 7;
      const float4* gp = (const float4*)(g0 + (long)row * p.lda + slot * 8);
      float4 v0 = gp[0], v1 = gp[1];
      aR[i * 8 + 0] = v0.x; aR[i * 8 + 1] = v0.y; aR[i * 8 + 2] = v0.z; aR[i * 8 + 3] = v0.w;
      aR[i * 8 + 4] = v1.x; aR[i * 8 + 5] = v1.y; aR[i * 8 + 6] = v1.z; aR[i * 8 + 7] = v1.w;
    }
  };
  auto writeA = [&](int buf) {
#pragma unroll
    for (int i = 0; i < 4; ++i) {
      int c = i * 256 + t;
      int row = c >> 3, slot = c & 7;
      short8 o;
#pragma unroll
      for (int j = 0; j < 8; ++j) o[j] = (short)f2bf(aR[i * 8 + j]);
      *(short8*)&lds[buf][0][row * 64 + ((slot ^ (row & 7)) * 8)] = o;
    }
  };
  auto compute = [&](int buf) {
    const u16* At  = lds[buf][0];
    const u16* Btl = lds[buf][1];
#pragma unroll
    for (int ks = 0; ks < 2; ++ks) {
      short8 af[4], bfr[4];
#pragma unroll
      for (int mi = 0; mi < 4; ++mi) {
        int row = wr * 64 + mi * 16 + (l & 15);
        int slot = (ks * 4 + (l >> 4)) ^ (row & 7);
        af[mi] = *(const short8*)&At[row * 64 + slot * 8];
      }
#pragma unroll
      for (int ni = 0; ni < 4; ++ni) {
        int row = wc * 64 + ni * 16 + (l & 15);
        int slot = (ks * 4 + (l >> 4)) ^ (row & 7);
        bfr[ni] = *(const short8*)&Btl[row * 64 + slot * 8];
      }
#pragma unroll
      for (int mi = 0; mi < 4; ++mi)
#pragma unroll
        for (int ni = 0; ni < 4; ++ni)
          acc[mi][ni] = __builtin_amdgcn_mfma_f32_16x16x32_bf16(
              af[mi], bfr[ni], acc[mi][ni], 0, 0, 0);
    }
  };

  const int nkt = p.K / BK;
  if (AF32) { loadA_f32(0); stageB(0, 0); writeA(0); }
  else      { stageA_bf16(0, 0); stageB(0, 0); }
  __syncthreads();

  int buf = 0;
  for (int kt = 0; kt < nkt; ++kt) {
    if (kt + 1 < nkt) {
      if (AF32) loadA_f32(kt + 1); else stageA_bf16(kt + 1, buf ^ 1);
      stageB(kt + 1, buf ^ 1);
    }
    compute(buf);
    if (AF32 && kt + 1 < nkt) writeA(buf ^ 1);
    __syncthreads();
    buf ^= 1;
  }

  const int cl = l & 15, rj = (l >> 4) * 4;
#pragma unroll
  for (int mi = 0; mi < 4; ++mi) {
#pragma unroll
    for (int ni = 0; ni < 4; ++ni) {
      int cidx = tn + wc * 64 + ni * 16 + cl;
      float bv = p.bias ? p.bias[cidx] : 0.f;
#pragma unroll
      for (int j = 0; j < 4; ++j) {
        int r = tm + wr * 64 + mi * 16 + rj + j;
        float v = acc[mi][ni][j] * p.scale + bv;
        if (p.mode == 2) {
          // VT[b][cidx][s]: b = r>>10, s = r&1023
          ((u16*)p.C)[((long)(r >> 10)) * 524288 + (long)cidx * 1024 + (r & 1023)] = f2bf(v);
        } else {
          long idx = (long)r * p.ldc + cidx;
          if (p.mode == 1) ((u16*)p.C)[idx] = f2bf(v);
          else             ((float*)p.C)[idx] = v;
        }
      }
    }
  }
}

// ---------------- fused scores -> softmax -> PV (swapped-MFMA, paired phases) -----
// grid (32 qblocks, 64 b*h), 512 threads = 8 waves (wq 0..1, wcol 0..3).
// Scores: 8 pair-phases (kv[2][2] ring). PV: 8 pair-phases (same ring) with P
// pairs through p4[2][2]. red (512B) aliases p4[1] (dead until P2/P3 arrive).
// Sync: only {stage/pwrite next; compute cur; __syncthreads()}.
__global__ __launch_bounds__(512, 4)
void fused_attn_kernel(const u16* __restrict__ Qg, const u16* __restrict__ Kg,
                       const u16* __restrict__ Vg, float* __restrict__ attnF,
                       u16* __restrict__ AO) {
  __shared__ __align__(16) u16 kv[2][2][64 * 128];  // 64 KB (pair ring)
  __shared__ __align__(16) u16 p4[2][2][32 * 64];   // 16 KB: Q stage / P pair ring
  float* red = (float*)&p4[1][0][0];                // [4][32] floats, aliases p4[1]

  const int t = threadIdx.x;
  const int w = t >> 6, l = t & 63;
  const int wq = w >> 2, wcol = w & 3;
  const int qb = blockIdx.x, z = blockIdx.y;
  const int b = z >> 4, h = z & 15, g = h >> 2;
  const int q0 = qb * 32;
  const int qi = wq * 16 + (l & 15);       // this lane's q row (local)

  const u16* Qbase = Qg + ((long)b * 1024 + q0) * 2048 + h * 128;
  const u16* Kbase = Kg + (long)b * 1024 * 512 + g * 128;
  const u16* Vbase = Vg + ((long)b * 512 + g * 128) * 1024;  // VT: rows=d, cols=s
  float* attnO = attnF + ((long)z * 1024 + q0) * 1024;

  auto glds16 = [](const u16* gp, u16* lp) {
    __builtin_amdgcn_global_load_lds(
        (const __attribute__((address_space(1))) unsigned int*)gp,
        (__attribute__((address_space(3))) unsigned int*)lp, 16, 0, 0);
  };
  auto stageK = [&](int c, int pb, int sub) {  // [64 s][16 blocks of 8 d]
#pragma unroll
    for (int i = 0; i < 2; ++i) {
      int idx = i * 512 + t;
      int row = idx >> 4, blk = idx & 15;
      glds16(Kbase + (long)(c * 64 + row) * 512 + ((blk ^ (row & 7)) * 8),
             &kv[pb][sub][(i * 512 + w * 64) * 8]);
    }
  };
  auto stageV = [&](int c, int pb, int sub) {  // [128 d][8 blocks of 8 s]
#pragma unroll
    for (int i = 0; i < 2; ++i) {
      int idx = i * 512 + t;
      int row = idx >> 3, blk = idx & 7;
      glds16(Vbase + (long)row * 1024 + c * 64 + ((blk ^ (row & 7)) * 8),
             &kv[pb][sub][(i * 512 + w * 64) * 8]);
    }
  };

  // prologue: Q (1 load/thread) into p4[0] (8 KB), K0+K1 into kv[0]
  {
    int row = t >> 4, blk = t & 15;
    glds16(Qbase + (long)row * 2048 + ((blk ^ (row & 7)) * 8), &((u16*)p4)[(w * 64) * 8]);
  }
  stageK(0, 0, 0);
  stageK(1, 0, 1);
  __syncthreads();

  short8 qf[4];
  {
    const u16* pq = (const u16*)p4;
#pragma unroll
    for (int ks = 0; ks < 4; ++ks) {
      int slot = (ks * 4 + (l >> 4)) ^ (qi & 7);
      qf[ks] = *(const short8*)&pq[qi * 128 + slot * 8];
    }
  }

  f32x4 acc[16];
#pragma unroll
  for (int c = 0; c < 16; ++c) acc[c] = (f32x4){0.f, 0.f, 0.f, 0.f};

  // ---- scores: 8 pair-phases; acc[c] = S[k = c*64 + wcol*16 + (l>>4)*4+j][q = qi]
  const int krow = wcol * 16 + (l & 15);
#pragma unroll
  for (int pph = 0; pph < 8; ++pph) {
    if (pph < 7) {
      stageK(2 * pph + 2, (pph + 1) & 1, 0);
      stageK(2 * pph + 3, (pph + 1) & 1, 1);
    } else {
      stageV(0, 0, 0);   // kv[0] free since pair-phase 6
      stageV(1, 0, 1);
    }
    __builtin_amdgcn_s_setprio(1);
#pragma unroll
    for (int sub = 0; sub < 2; ++sub) {
      const int c = 2 * pph + sub;
      const u16* Kl = kv[pph & 1][sub];
#pragma unroll
      for (int ks = 0; ks < 4; ++ks) {
        int slot = (ks * 4 + (l >> 4)) ^ (krow & 7);
        short8 kf = *(const short8*)&Kl[krow * 128 + slot * 8];
        acc[c] = __builtin_amdgcn_mfma_f32_16x16x32_bf16(kf, qf[ks], acc[c], 0, 0, 0);
      }
    }
    __builtin_amdgcn_s_setprio(0);
    __syncthreads();                       // drains stages; next pair ready
  }

  // ---- softmax: per-lane (64 vals) + 2 shfl + cross-wave reduce via red (1 buffer)
  const float scale = 0.08838834764831845f;  // 1/sqrt(128)
  float jm[4] = {-1e30f, -1e30f, -1e30f, -1e30f};
#pragma unroll
  for (int c = 0; c < 16; ++c) {
#pragma unroll
    for (int j = 0; j < 4; ++j) jm[j] = fmaxf(jm[j], acc[c][j]);
  }
  float mx = fmaxf(fmaxf(jm[0], jm[1]), fmaxf(jm[2], jm[3]));
  mx = fmaxf(mx, __shfl_xor(mx, 16));
  mx = fmaxf(mx, __shfl_xor(mx, 32));
  if ((l >> 4) == 0) red[wcol * 32 + qi] = mx;
  __syncthreads();
  const float m = fmaxf(fmaxf(red[0 * 32 + qi], red[1 * 32 + qi]),
                        fmaxf(red[2 * 32 + qi], red[3 * 32 + qi]));
  __syncthreads();   // protect red reuse (single buffer)
  float s4[4] = {0.f, 0.f, 0.f, 0.f};
#pragma unroll
  for (int c = 0; c < 16; ++c) {
#pragma unroll
    for (int j = 0; j < 4; ++j) {
      float e = __expf((acc[c][j] - m) * scale);
      acc[c][j] = e;
      s4[j] += e;
    }
  }
  float ss = (s4[0] + s4[1]) + (s4[2] + s4[3]);
  ss += __shfl_xor(ss, 16);
  ss += __shfl_xor(ss, 32);
  if ((l >> 4) == 0) red[wcol * 32 + qi] = ss;
  __syncthreads();
  const float inv = 1.0f / (red[0 * 32 + qi] + red[1 * 32 + qi] +
                            red[2 * 32 + qi] + red[3 * 32 + qi]);

  // ---- normalize in place + float4 attn stores (acc[] now holds P)
#pragma unroll
  for (int c = 0; c < 16; ++c) {
    acc[c] = acc[c] * inv;
    *(f32x4*)(attnO + (long)qi * 1024 + c * 64 + wcol * 16 + ((l >> 4) * 4)) = acc[c];
  }

  // ---- PV: 8 pair-phases; P pairs through p4 ring, packed at write time
  const int kloc = wcol * 16 + ((l >> 4) * 4);       // k-position within chunk
  auto pwrite = [&](u16* dst, const f32x4& a) {
    int blk = (kloc >> 3) ^ (qi & 7);
    uint2 val;
    val.x = (unsigned)f2bf(a[0]) | ((unsigned)f2bf(a[1]) << 16);
    val.y = (unsigned)f2bf(a[2]) | ((unsigned)f2bf(a[3]) << 16);
    *(uint2*)&dst[qi * 64 + blk * 8 + (kloc & 7)] = val;
  };

  pwrite(p4[0][0], acc[0]);      // P0,P1 -> p4[0] (Q dead; red still intact in p4[1])
  pwrite(p4[0][1], acc[1]);
  __syncthreads();               // P0/P1 visible; V0/V1 (staged at pph=7) drained

  f32x4 acc2[2] = {};
  const int prow = wq * 16 + (l & 15);
#pragma unroll
  for (int pp = 0; pp < 8; ++pp) {
    if (pp < 7) {
      pwrite(p4[(pp + 1) & 1][0], acc[2 * pp + 2]);  // red dead from here on
      pwrite(p4[(pp + 1) & 1][1], acc[2 * pp + 3]);
      stageV(2 * pp + 2, (pp + 1) & 1, 0);
      stageV(2 * pp + 3, (pp + 1) & 1, 1);
    }
    __builtin_amdgcn_s_setprio(1);
#pragma unroll
    for (int sub = 0; sub < 2; ++sub) {
      const u16* Vl = kv[pp & 1][sub];
      const u16* Pl = p4[pp & 1][sub];
#pragma unroll
      for (int ks = 0; ks < 2; ++ks) {
        int ablk = (ks * 4 + (l >> 4)) ^ (prow & 7);
        short8 af = *(const short8*)&Pl[prow * 64 + ablk * 8];
#pragma unroll
        for (int ni = 0; ni < 2; ++ni) {
          int vrow = wcol * 32 + ni * 16 + (l & 15);
          int vslot = (ks * 4 + (l >> 4)) ^ (vrow & 7);
          short8 vf = *(const short8*)&Vl[vrow * 64 + vslot * 8];
          acc2[ni] = __builtin_amdgcn_mfma_f32_16x16x32_bf16(af, vf, acc2[ni], 0, 0, 0);
        }
      }
    }
    __builtin_amdgcn_s_setprio(0);
    __syncthreads();             // drains stages + pwrites; next pair ready
  }

  // ---- write AO (bf16): q = wq*16 + (l>>4)*4 + j, d = wcol*32 + ni*16 + (l&15)
  u16* AObase = AO + ((long)b * 1024 + q0) * 2048 + h * 128;
#pragma unroll
  for (int ni = 0; ni < 2; ++ni)
#pragma unroll
    for (int j = 0; j < 4; ++j) {
      int qq = wq * 16 + (l >> 4) * 4 + j;
      int d = wcol * 32 + ni * 16 + (l & 15);
      AObase[(long)qq * 2048 + d] = f2bf(acc2[ni][j]);
    }
}

// ---------------- host ----------------
extern "C" void kernel_launch(void* const* d_in, const int* in_sizes, int n_in,
                              void* d_out, int out_size, void* d_ws, size_t ws_size,
                              hipStream_t stream) {
  const float* query = (const float*)d_in[0];
  const float* key_  = (const float*)d_in[1];
  const float* value = (const float*)d_in[2];
  const float* Wq = (const float*)d_in[3]; const float* bq = (const float*)d_in[4];
  const float* Wk = (const float*)d_in[5]; const float* bk = (const float*)d_in[6];
  const float* Wv = (const float*)d_in[7]; const float* bv = (const float*)d_in[8];
  const float* Wo = (const float*)d_in[9]; const float* bo = (const float*)d_in[10];

  float* outF  = (float*)d_out;                 // [4,1024,2048]
  float* attnF = outF + 8388608;                // [4,16,1024,1024]

  char* wp = (char*)d_ws;
  u16* WqT = (u16*)wp; wp += 2048L * 2048 * 2;
  u16* WkT = (u16*)wp; wp += 512L * 2048 * 2;
  u16* WvT = (u16*)wp; wp += 512L * 2048 * 2;
  u16* WoT = (u16*)wp; wp += 2048L * 2048 * 2;
  u16* Qb  = (u16*)wp; wp += 4096L * 2048 * 2;
  u16* Kb  = (u16*)wp; wp += 4096L * 512 * 2;
  u16* VT  = (u16*)wp; wp += 4L * 512 * 1024 * 2;
  u16* AO  = (u16*)wp; wp += 4096L * 2048 * 2;

  // merged weight transposes (Wq, Wk, Wv, Wo)
  TP4 tp;
  tp.s0 = Wq; tp.s1 = Wk; tp.s2 = Wv; tp.s3 = Wo;
  tp.d0 = WqT; tp.d1 = WkT; tp.d2 = WvT; tp.d3 = WoT;
  transpose4_kernel<<<dim3(64, 64, 4), dim3(32, 8), 0, stream>>>(tp);

  // merged Q/K/V projections: 512 + 128 + 128 = 768 blocks, XCD-swizzled
  Gemm3 g = {};
  g.q[0].A = query; g.q[0].B = WqT; g.q[0].bias = bq; g.q[0].C = Qb;
  g.q[0].N = 2048; g.q[0].K = 2048; g.q[0].lda = 2048; g.q[0].ldb = 2048;
  g.q[0].ldc = 2048; g.q[0].mode = 1; g.q[0].scale = 1.f;
  g.q[1].A = key_; g.q[1].B = WkT; g.q[1].bias = bk; g.q[1].C = Kb;
  g.q[1].N = 512; g.q[1].K = 2048; g.q[1].lda = 2048; g.q[1].ldb = 2048;
  g.q[1].ldc = 512; g.q[1].mode = 1; g.q[1].scale = 1.f;
  g.q[2].A = value; g.q[2].B = WvT; g.q[2].bias = bv; g.q[2].C = VT;
  g.q[2].N = 512; g.q[2].K = 2048; g.q[2].lda = 2048; g.q[2].ldb = 2048;
  g.q[2].ldc = 1024; g.q[2].mode = 2; g.q[2].scale = 1.f;
  g.nb0 = 512; g.nb1 = 128; g.nwg = 768;
  gemm3_kernel<true><<<dim3(768), 256, 0, stream>>>(g);

  // fused scores/softmax/PV
  fused_attn_kernel<<<dim3(32, 64), 512, 0, stream>>>(Qb, Kb, VT, attnF, AO);

  // O projection: AO [4096,2048] x WoT + bo -> outF fp32 (XCD-swizzled)
  Gemm3 go = {};
  go.q[0].A = AO; go.q[0].B = WoT; go.q[0].bias = bo; go.q[0].C = outF;
  go.q[0].N = 2048; go.q[0].K = 2048; go.q[0].lda = 2048; go.q[0].ldb = 2048;
  go.q[0].ldc = 2048; go.q[0].mode = 0; go.q[0].scale = 1.f;
  go.nb0 = 512; go.nb1 = 0; go.nwg = 512;
  gemm3_kernel<false><<<dim3(512), 256, 0, stream>>>(go);
}

// Round 10
// 295.120 us; speedup vs baseline: 1.6085x; 1.0137x over previous
//
#include <hip/hip_runtime.h>
#include <hip/hip_bf16.h>

typedef unsigned short u16;
typedef __attribute__((ext_vector_type(8))) short short8;
typedef __attribute__((ext_vector_type(4))) float f32x4;

__device__ __forceinline__ u16 f2bf(float f) {
  __hip_bfloat16 h = __float2bfloat16(f);   // HW RNE; compiler packs to v_cvt_pk_bf16_f32
  return *reinterpret_cast<u16*>(&h);
}

// ---------------- merged weight transpose+cvt: dst[c][r] = (bf16)W[r][c] ----------
struct TP4 {
  const float *s0, *s1, *s2, *s3;
  u16 *d0, *d1, *d2, *d3;
};
__global__ __launch_bounds__(256)
void transpose4_kernel(TP4 tp) {
  const int z = blockIdx.z;
  const float* sf; u16* dst; int C;
  if      (z == 0) { sf = tp.s0; dst = tp.d0; C = 2048; }
  else if (z == 1) { sf = tp.s1; dst = tp.d1; C = 512;  }
  else if (z == 2) { sf = tp.s2; dst = tp.d2; C = 512;  }
  else             { sf = tp.s3; dst = tp.d3; C = 2048; }
  const int c0 = blockIdx.x * 32, r0 = blockIdx.y * 32;
  if (c0 >= C) return;
  const int R = 2048;
  __shared__ u16 tile[32][33];
  const int tx = threadIdx.x, ty = threadIdx.y;
#pragma unroll
  for (int i = 0; i < 4; ++i) {
    int r = r0 + ty + i * 8;
    tile[ty + i * 8][tx] = f2bf(sf[(long)r * C + c0 + tx]);
  }
  __syncthreads();
#pragma unroll
  for (int i = 0; i < 4; ++i) {
    int rr = ty + i * 8;
    dst[(long)(c0 + rr) * R + r0 + tx] = tile[tx][rr];
  }
}

// ---------------- GEMM (up to 3 independent problems per dispatch) ----------------
// C[m][n] = scale * sum_k A[m][k] * Bt[n][k] + bias[n]
// mode: 0 = f32 store, 1 = bf16 store, 2 = bf16 transposed-batched (VT[b][n][s])
#define BM 128
#define BN 128
#define BK 64

struct GemmP {
  const void* A;
  const u16* B;
  const float* bias;
  void* C;
  int N, K, lda, ldb, ldc, mode;
  float scale;
};
struct Gemm3 {
  GemmP q[3];
  int nb0, nb1;   // block counts of problems 0 and 1
  int nwg;        // total blocks (divisible by 8)
};

template<bool AF32>
__global__ __launch_bounds__(256, 2)
void gemm3_kernel(Gemm3 g) {
  __shared__ __align__(16) u16 lds[2][2][BM * BK];
  const int t = threadIdx.x;
  const int w = t >> 6, l = t & 63;

  // bijective XCD swizzle (nwg % 8 == 0)
  const int cpx = g.nwg >> 3;
  const int swz = (blockIdx.x & 7) * cpx + (blockIdx.x >> 3);
  int pi, local;
  if (swz < g.nb0)            { pi = 0; local = swz; }
  else if (swz < g.nb0 + g.nb1) { pi = 1; local = swz - g.nb0; }
  else                        { pi = 2; local = swz - g.nb0 - g.nb1; }
  const GemmP p = g.q[pi];

  const int nTn = p.N / BN;
  const int tm = (local / nTn) * BM;
  const int tn = (local % nTn) * BN;

  const u16*   Ab = (const u16*)p.A + (long)tm * p.lda;
  const float* Af = (const float*)p.A + (long)tm * p.lda;
  const u16*   Bt = p.B + (long)tn * p.ldb;

  const int wr = w >> 1, wc = w & 1;
  f32x4 acc[4][4] = {};
  float aR[32];

  auto stageB = [&](int kt, int buf) {
#pragma unroll
    for (int i = 0; i < 4; ++i) {
      int c = i * 256 + t;
      int row = c >> 3;
      int slot = (c & 7) ^ (row & 7);
      const u16* gp = Bt + kt * BK + (long)row * p.ldb + slot * 8;
      u16* lp = &lds[buf][1][(i * 256 + w * 64) * 8];
      __builtin_amdgcn_global_load_lds(
          (const __attribute__((address_space(1))) unsigned int*)gp,
          (__attribute__((address_space(3))) unsigned int*)lp, 16, 0, 0);
    }
  };
  auto stageA_bf16 = [&](int kt, int buf) {
#pragma unroll
    for (int i = 0; i < 4; ++i) {
      int c = i * 256 + t;
      int row = c >> 3;
      int slot = (c & 7) ^ (row & 7);
      const u16* gp = Ab + kt * BK + (long)row * p.lda + slot * 8;
      u16* lp = &lds[buf][0][(i * 256 + w * 64) * 8];
      __builtin_amdgcn_global_load_lds(
          (const __attribute__((address_space(1))) unsigned int*)gp,
          (__attribute__((address_space(3))) unsigned int*)lp, 16, 0, 0);
    }
  };
  auto loadA_f32 = [&](int kt) {
    const float* g0 = Af + kt * BK;
#pragma unroll
    for (int i = 0; i < 4; ++i) {
      int c = i * 256 + t;
      int row = c >> 3, slot = c & 7;
      const float4* gp = (const float4*)(g0 + (long)row * p.lda + slot * 8);
      float4 v0 = gp[0], v1 = gp[1];
      aR[i * 8 + 0] = v0.x; aR[i * 8 + 1] = v0.y; aR[i * 8 + 2] = v0.z; aR[i * 8 + 3] = v0.w;
      aR[i * 8 + 4] = v1.x; aR[i * 8 + 5] = v1.y; aR[i * 8 + 6] = v1.z; aR[i * 8 + 7] = v1.w;
    }
  };
  auto writeA = [&](int buf) {
#pragma unroll
    for (int i = 0; i < 4; ++i) {
      int c = i * 256 + t;
      int row = c >> 3, slot = c & 7;
      short8 o;
#pragma unroll
      for (int j = 0; j < 8; ++j) o[j] = (short)f2bf(aR[i * 8 + j]);
      *(short8*)&lds[buf][0][row * 64 + ((slot ^ (row & 7)) * 8)] = o;
    }
  };
  auto compute = [&](int buf) {
    const u16* At  = lds[buf][0];
    const u16* Btl = lds[buf][1];
#pragma unroll
    for (int ks = 0; ks < 2; ++ks) {
      short8 af[4], bfr[4];
#pragma unroll
      for (int mi = 0; mi < 4; ++mi) {
        int row = wr * 64 + mi * 16 + (l & 15);
        int slot = (ks * 4 + (l >> 4)) ^ (row & 7);
        af[mi] = *(const short8*)&At[row * 64 + slot * 8];
      }
#pragma unroll
      for (int ni = 0; ni < 4; ++ni) {
        int row = wc * 64 + ni * 16 + (l & 15);
        int slot = (ks * 4 + (l >> 4)) ^ (row & 7);
        bfr[ni] = *(const short8*)&Btl[row * 64 + slot * 8];
      }
#pragma unroll
      for (int mi = 0; mi < 4; ++mi)
#pragma unroll
        for (int ni = 0; ni < 4; ++ni)
          acc[mi][ni] = __builtin_amdgcn_mfma_f32_16x16x32_bf16(
              af[mi], bfr[ni], acc[mi][ni], 0, 0, 0);
    }
  };

  const int nkt = p.K / BK;
  if (AF32) { loadA_f32(0); stageB(0, 0); writeA(0); }
  else      { stageA_bf16(0, 0); stageB(0, 0); }
  __syncthreads();

  int buf = 0;
  for (int kt = 0; kt < nkt; ++kt) {
    if (kt + 1 < nkt) {
      if (AF32) loadA_f32(kt + 1); else stageA_bf16(kt + 1, buf ^ 1);
      stageB(kt + 1, buf ^ 1);
    }
    compute(buf);
    if (AF32 && kt + 1 < nkt) writeA(buf ^ 1);
    __syncthreads();
    buf ^= 1;
  }

  const int cl = l & 15, rj = (l >> 4) * 4;
#pragma unroll
  for (int mi = 0; mi < 4; ++mi) {
#pragma unroll
    for (int ni = 0; ni < 4; ++ni) {
      int cidx = tn + wc * 64 + ni * 16 + cl;
      float bv = p.bias ? p.bias[cidx] : 0.f;
#pragma unroll
      for (int j = 0; j < 4; ++j) {
        int r = tm + wr * 64 + mi * 16 + rj + j;
        float v = acc[mi][ni][j] * p.scale + bv;
        if (p.mode == 2) {
          // VT[b][cidx][s]: b = r>>10, s = r&1023
          ((u16*)p.C)[((long)(r >> 10)) * 524288 + (long)cidx * 1024 + (r & 1023)] = f2bf(v);
        } else {
          long idx = (long)r * p.ldc + cidx;
          if (p.mode == 1) ((u16*)p.C)[idx] = f2bf(v);
          else             ((float*)p.C)[idx] = v;
        }
      }
    }
  }
}

// ---------------- fused scores -> softmax -> PV (swapped-MFMA, paired phases) -----
// grid (32 qblocks, 64 b*h), 512 threads = 8 waves (wq 0..1, wcol 0..3).
// Scores: 8 pair-phases (kv[2][2] ring). PV: 8 pair-phases (same ring) with P
// pairs through p4[2][2]. red (512B) aliases p4[1] (dead until P2/P3 arrive).
// attn f32 stores issued AFTER the PV loop so no phase barrier drains them.
// Sync: only {stage/pwrite next; compute cur; __syncthreads()}.
__global__ __launch_bounds__(512, 4)
void fused_attn_kernel(const u16* __restrict__ Qg, const u16* __restrict__ Kg,
                       const u16* __restrict__ Vg, float* __restrict__ attnF,
                       u16* __restrict__ AO) {
  __shared__ __align__(16) u16 kv[2][2][64 * 128];  // 64 KB (pair ring)
  __shared__ __align__(16) u16 p4[2][2][32 * 64];   // 16 KB: Q stage / P pair ring
  float* red = (float*)&p4[1][0][0];                // [4][32] floats, aliases p4[1]

  const int t = threadIdx.x;
  const int w = t >> 6, l = t & 63;
  const int wq = w >> 2, wcol = w & 3;
  const int qb = blockIdx.x, z = blockIdx.y;
  const int b = z >> 4, h = z & 15, g = h >> 2;
  const int q0 = qb * 32;
  const int qi = wq * 16 + (l & 15);       // this lane's q row (local)

  const u16* Qbase = Qg + ((long)b * 1024 + q0) * 2048 + h * 128;
  const u16* Kbase = Kg + (long)b * 1024 * 512 + g * 128;
  const u16* Vbase = Vg + ((long)b * 512 + g * 128) * 1024;  // VT: rows=d, cols=s
  float* attnO = attnF + ((long)z * 1024 + q0) * 1024;

  auto glds16 = [](const u16* gp, u16* lp) {
    __builtin_amdgcn_global_load_lds(
        (const __attribute__((address_space(1))) unsigned int*)gp,
        (__attribute__((address_space(3))) unsigned int*)lp, 16, 0, 0);
  };
  auto stageK = [&](int c, int pb, int sub) {  // [64 s][16 blocks of 8 d]
#pragma unroll
    for (int i = 0; i < 2; ++i) {
      int idx = i * 512 + t;
      int row = idx >> 4, blk = idx & 15;
      glds16(Kbase + (long)(c * 64 + row) * 512 + ((blk ^ (row & 7)) * 8),
             &kv[pb][sub][(i * 512 + w * 64) * 8]);
    }
  };
  auto stageV = [&](int c, int pb, int sub) {  // [128 d][8 blocks of 8 s]
#pragma unroll
    for (int i = 0; i < 2; ++i) {
      int idx = i * 512 + t;
      int row = idx >> 3, blk = idx & 7;
      glds16(Vbase + (long)row * 1024 + c * 64 + ((blk ^ (row & 7)) * 8),
             &kv[pb][sub][(i * 512 + w * 64) * 8]);
    }
  };

  // prologue: Q (1 load/thread) into p4[0] (8 KB), K0+K1 into kv[0]
  {
    int row = t >> 4, blk = t & 15;
    glds16(Qbase + (long)row * 2048 + ((blk ^ (row & 7)) * 8), &((u16*)p4)[(w * 64) * 8]);
  }
  stageK(0, 0, 0);
  stageK(1, 0, 1);
  __syncthreads();

  short8 qf[4];
  {
    const u16* pq = (const u16*)p4;
#pragma unroll
    for (int ks = 0; ks < 4; ++ks) {
      int slot = (ks * 4 + (l >> 4)) ^ (qi & 7);
      qf[ks] = *(const short8*)&pq[qi * 128 + slot * 8];
    }
  }

  f32x4 acc[16];
#pragma unroll
  for (int c = 0; c < 16; ++c) acc[c] = (f32x4){0.f, 0.f, 0.f, 0.f};

  // ---- scores: 8 pair-phases; acc[c] = S[k = c*64 + wcol*16 + (l>>4)*4+j][q = qi]
  const int krow = wcol * 16 + (l & 15);
#pragma unroll
  for (int pph = 0; pph < 8; ++pph) {
    if (pph < 7) {
      stageK(2 * pph + 2, (pph + 1) & 1, 0);
      stageK(2 * pph + 3, (pph + 1) & 1, 1);
    } else {
      stageV(0, 0, 0);   // kv[0] free since pair-phase 6
      stageV(1, 0, 1);
    }
    __builtin_amdgcn_s_setprio(1);
#pragma unroll
    for (int sub = 0; sub < 2; ++sub) {
      const int c = 2 * pph + sub;
      const u16* Kl = kv[pph & 1][sub];
#pragma unroll
      for (int ks = 0; ks < 4; ++ks) {
        int slot = (ks * 4 + (l >> 4)) ^ (krow & 7);
        short8 kf = *(const short8*)&Kl[krow * 128 + slot * 8];
        acc[c] = __builtin_amdgcn_mfma_f32_16x16x32_bf16(kf, qf[ks], acc[c], 0, 0, 0);
      }
    }
    __builtin_amdgcn_s_setprio(0);
    __syncthreads();                       // drains stages; next pair ready
  }

  // ---- softmax: per-lane (64 vals) + 2 shfl + cross-wave reduce via red (1 buffer)
  const float scale = 0.08838834764831845f;  // 1/sqrt(128)
  float jm[4] = {-1e30f, -1e30f, -1e30f, -1e30f};
#pragma unroll
  for (int c = 0; c < 16; ++c) {
#pragma unroll
    for (int j = 0; j < 4; ++j) jm[j] = fmaxf(jm[j], acc[c][j]);
  }
  float mx = fmaxf(fmaxf(jm[0], jm[1]), fmaxf(jm[2], jm[3]));
  mx = fmaxf(mx, __shfl_xor(mx, 16));
  mx = fmaxf(mx, __shfl_xor(mx, 32));
  if ((l >> 4) == 0) red[wcol * 32 + qi] = mx;
  __syncthreads();
  const float m = fmaxf(fmaxf(red[0 * 32 + qi], red[1 * 32 + qi]),
                        fmaxf(red[2 * 32 + qi], red[3 * 32 + qi]));
  __syncthreads();   // protect red reuse (single buffer)
  float s4[4] = {0.f, 0.f, 0.f, 0.f};
#pragma unroll
  for (int c = 0; c < 16; ++c) {
#pragma unroll
    for (int j = 0; j < 4; ++j) {
      float e = __expf((acc[c][j] - m) * scale);
      acc[c][j] = e;
      s4[j] += e;
    }
  }
  float ss = (s4[0] + s4[1]) + (s4[2] + s4[3]);
  ss += __shfl_xor(ss, 16);
  ss += __shfl_xor(ss, 32);
  if ((l >> 4) == 0) red[wcol * 32 + qi] = ss;
  __syncthreads();
  const float inv = 1.0f / (red[0 * 32 + qi] + red[1 * 32 + qi] +
                            red[2 * 32 + qi] + red[3 * 32 + qi]);

  // ---- normalize in place (acc[] now holds P); attn stores deferred to after PV
#pragma unroll
  for (int c = 0; c < 16; ++c) acc[c] = acc[c] * inv;

  // ---- PV: 8 pair-phases; P pairs through p4 ring, packed at write time
  const int kloc = wcol * 16 + ((l >> 4) * 4);       // k-position within chunk
  auto pwrite = [&](u16* dst, const f32x4& a) {
    int blk = (kloc >> 3) ^ (qi & 7);
    uint2 val;
    val.x = (unsigned)f2bf(a[0]) | ((unsigned)f2bf(a[1]) << 16);
    val.y = (unsigned)f2bf(a[2]) | ((unsigned)f2bf(a[3]) << 16);
    *(uint2*)&dst[qi * 64 + blk * 8 + (kloc & 7)] = val;
  };

  pwrite(p4[0][0], acc[0]);      // P0,P1 -> p4[0] (Q dead; red still intact in p4[1])
  pwrite(p4[0][1], acc[1]);
  __syncthreads();               // P0/P1 visible; V0/V1 (staged at pph=7) drained

  f32x4 acc2[2] = {};
  const int prow = wq * 16 + (l & 15);
#pragma unroll
  for (int pp = 0; pp < 8; ++pp) {
    if (pp < 7) {
      pwrite(p4[(pp + 1) & 1][0], acc[2 * pp + 2]);  // red dead from here on
      pwrite(p4[(pp + 1) & 1][1], acc[2 * pp + 3]);
      stageV(2 * pp + 2, (pp + 1) & 1, 0);
      stageV(2 * pp + 3, (pp + 1) & 1, 1);
    }
    __builtin_amdgcn_s_setprio(1);
#pragma unroll
    for (int sub = 0; sub < 2; ++sub) {
      const u16* Vl = kv[pp & 1][sub];
      const u16* Pl = p4[pp & 1][sub];
#pragma unroll
      for (int ks = 0; ks < 2; ++ks) {
        int ablk = (ks * 4 + (l >> 4)) ^ (prow & 7);
        short8 af = *(const short8*)&Pl[prow * 64 + ablk * 8];
#pragma unroll
        for (int ni = 0; ni < 2; ++ni) {
          int vrow = wcol * 32 + ni * 16 + (l & 15);
          int vslot = (ks * 4 + (l >> 4)) ^ (vrow & 7);
          short8 vf = *(const short8*)&Vl[vrow * 64 + vslot * 8];
          acc2[ni] = __builtin_amdgcn_mfma_f32_16x16x32_bf16(af, vf, acc2[ni], 0, 0, 0);
        }
      }
    }
    __builtin_amdgcn_s_setprio(0);
    __syncthreads();             // drains stages + pwrites; next pair ready
  }

  // ---- deferred attn (f32) stores: float4 per chunk, no barrier will wait on them
#pragma unroll
  for (int c = 0; c < 16; ++c)
    *(f32x4*)(attnO + (long)qi * 1024 + c * 64 + wcol * 16 + ((l >> 4) * 4)) = acc[c];

  // ---- write AO (bf16): q = wq*16 + (l>>4)*4 + j, d = wcol*32 + ni*16 + (l&15)
  u16* AObase = AO + ((long)b * 1024 + q0) * 2048 + h * 128;
#pragma unroll
  for (int ni = 0; ni < 2; ++ni)
#pragma unroll
    for (int j = 0; j < 4; ++j) {
      int qq = wq * 16 + (l >> 4) * 4 + j;
      int d = wcol * 32 + ni * 16 + (l & 15);
      AObase[(long)qq * 2048 + d] = f2bf(acc2[ni][j]);
    }
}

// ---------------- host ----------------
extern "C" void kernel_launch(void* const* d_in, const int* in_sizes, int n_in,
                              void* d_out, int out_size, void* d_ws, size_t ws_size,
                              hipStream_t stream) {
  const float* query = (const float*)d_in[0];
  const float* key_  = (const float*)d_in[1];
  const float* value = (const float*)d_in[2];
  const float* Wq = (const float*)d_in[3]; const float* bq = (const float*)d_in[4];
  const float* Wk = (const float*)d_in[5]; const float* bk = (const float*)d_in[6];
  const float* Wv = (const float*)d_in[7]; const float* bv = (const float*)d_in[8];
  const float* Wo = (const float*)d_in[9]; const float* bo = (const float*)d_in[10];

  float* outF  = (float*)d_out;                 // [4,1024,2048]
  float* attnF = outF + 8388608;                // [4,16,1024,1024]

  char* wp = (char*)d_ws;
  u16* WqT = (u16*)wp; wp += 2048L * 2048 * 2;
  u16* WkT = (u16*)wp; wp += 512L * 2048 * 2;
  u16* WvT = (u16*)wp; wp += 512L * 2048 * 2;
  u16* WoT = (u16*)wp; wp += 2048L * 2048 * 2;
  u16* Qb  = (u16*)wp; wp += 4096L * 2048 * 2;
  u16* Kb  = (u16*)wp; wp += 4096L * 512 * 2;
  u16* VT  = (u16*)wp; wp += 4L * 512 * 1024 * 2;
  u16* AO  = (u16*)wp; wp += 4096L * 2048 * 2;

  // merged weight transposes (Wq, Wk, Wv, Wo)
  TP4 tp;
  tp.s0 = Wq; tp.s1 = Wk; tp.s2 = Wv; tp.s3 = Wo;
  tp.d0 = WqT; tp.d1 = WkT; tp.d2 = WvT; tp.d3 = WoT;
  transpose4_kernel<<<dim3(64, 64, 4), dim3(32, 8), 0, stream>>>(tp);

  // merged Q/K/V projections: 512 + 128 + 128 = 768 blocks, XCD-swizzled
  Gemm3 g = {};
  g.q[0].A = query; g.q[0].B = WqT; g.q[0].bias = bq; g.q[0].C = Qb;
  g.q[0].N = 2048; g.q[0].K = 2048; g.q[0].lda = 2048; g.q[0].ldb = 2048;
  g.q[0].ldc = 2048; g.q[0].mode = 1; g.q[0].scale = 1.f;
  g.q[1].A = key_; g.q[1].B = WkT; g.q[1].bias = bk; g.q[1].C = Kb;
  g.q[1].N = 512; g.q[1].K = 2048; g.q[1].lda = 2048; g.q[1].ldb = 2048;
  g.q[1].ldc = 512; g.q[1].mode = 1; g.q[1].scale = 1.f;
  g.q[2].A = value; g.q[2].B = WvT; g.q[2].bias = bv; g.q[2].C = VT;
  g.q[2].N = 512; g.q[2].K = 2048; g.q[2].lda = 2048; g.q[2].ldb = 2048;
  g.q[2].ldc = 1024; g.q[2].mode = 2; g.q[2].scale = 1.f;
  g.nb0 = 512; g.nb1 = 128; g.nwg = 768;
  gemm3_kernel<true><<<dim3(768), 256, 0, stream>>>(g);

  // fused scores/softmax/PV
  fused_attn_kernel<<<dim3(32, 64), 512, 0, stream>>>(Qb, Kb, VT, attnF, AO);

  // O projection: AO [4096,2048] x WoT + bo -> outF fp32 (XCD-swizzled)
  Gemm3 go = {};
  go.q[0].A = AO; go.q[0].B = WoT; go.q[0].bias = bo; go.q[0].C = outF;
  go.q[0].N = 2048; go.q[0].K = 2048; go.q[0].lda = 2048; go.q[0].ldb = 2048;
  go.q[0].ldc = 2048; go.q[0].mode = 0; go.q[0].scale = 1.f;
  go.nb0 = 512; go.nb1 = 0; go.nwg = 512;
  gemm3_kernel<false><<<dim3(512), 256, 0, stream>>>(go);
}